// Round 1
// baseline (3959.187 us; speedup 1.0000x reference)
//
#include <hip/hip_runtime.h>
#include <math.h>

#define NN 8192
#define NE 131072
#define CIN 128
#define C 64
#define NL 4
#define COUT 21
#define EPSV 1e-5f

// ---------------------------------------------------------------- utilities
__global__ void zero_f32(float* p, int n) {
  int i = blockIdx.x * blockDim.x + threadIdx.x;
  if (i < n) p[i] = 0.f;
}

__global__ void deg_kernel(const int* __restrict__ dst, float* __restrict__ deg) {
  int e = blockIdx.x * 256 + threadIdx.x;
  if (e < NE) atomicAdd(&deg[dst[e]], 1.0f);
}

__global__ void dinv_kernel(float* __restrict__ d) {
  int i = blockIdx.x * 256 + threadIdx.x;
  if (i < NN) d[i] = rsqrtf(d[i] + 1.0f);  // +1 self loop; deg>=1 always
}

// ------------------------------------------------------------- input GEMM
__global__ __launch_bounds__(256) void gemm_in_kernel(const float* __restrict__ X,
                                                      const float* __restrict__ W,
                                                      const float* __restrict__ b,
                                                      float* __restrict__ Y) {
  int idx = blockIdx.x * 256 + threadIdx.x;   // N*64 threads
  int n = idx >> 6, c = idx & 63;
  const float* xr = X + n * CIN;
  float acc = b[c];
#pragma unroll 16
  for (int k = 0; k < CIN; ++k) acc = fmaf(xr[k], W[k * C + c], acc);
  Y[idx] = acc;
}

// ------------------------------------------------- generic small GEMM (thread/output)
// Y[n][m] = sum_k X[n][k] * (TB ? W[m][k] : W[k][m]) (+bias) (+res) (relu?)
template <int K, int M, bool TB, bool RELU, bool RES, bool BIAS>
__global__ __launch_bounds__(256) void gemm_k(const float* __restrict__ X,
                                              const float* __restrict__ W,
                                              const float* __restrict__ bias,
                                              const float* __restrict__ res,
                                              float* __restrict__ Y) {
  int idx = blockIdx.x * 256 + threadIdx.x;
  int n = idx / M, m = idx % M;
  const float* xr = X + n * K;
  float acc = BIAS ? bias[m] : 0.f;
#pragma unroll 16
  for (int k = 0; k < K; ++k) acc = fmaf(xr[k], TB ? W[m * K + k] : W[k * M + m], acc);
  if (RES) acc += res[idx];
  if (RELU) acc = fmaxf(acc, 0.f);
  Y[idx] = acc;
}

// qkv[n][j] = h[n][:] . Wqkv[j][:] + bqkv[j]   (j<64 -> q, <128 -> k, else v)
__global__ __launch_bounds__(256) void qkv_kernel(const float* __restrict__ H,
                                                  const float* __restrict__ Wq,
                                                  const float* __restrict__ bq,
                                                  float* __restrict__ q,
                                                  float* __restrict__ kk,
                                                  float* __restrict__ v) {
  int idx = blockIdx.x * 256 + threadIdx.x;   // N*192
  int n = idx / 192, j = idx % 192;
  const float* xr = H + n * C;
  float acc = bq[j];
#pragma unroll 16
  for (int c = 0; c < C; ++c) acc = fmaf(xr[c], Wq[j * C + c], acc);
  float* dp = (j < 64) ? q : (j < 128) ? kk : v;
  dp[n * 64 + (j & 63)] = acc;
}

// ---------------------------------------------------------------- GCN
// out = xw*dinv^2 (self loop) + b + h (residual); edges scatter-added after
__global__ __launch_bounds__(256) void gcn_init(const float* __restrict__ xw,
                                                const float* __restrict__ h,
                                                const float* __restrict__ gb,
                                                const float* __restrict__ dinv,
                                                float* __restrict__ out) {
  int idx = blockIdx.x * 256 + threadIdx.x;
  int n = idx >> 6, c = idx & 63;
  float di = dinv[n];
  out[idx] = xw[idx] * di * di + gb[c] + h[idx];
}

__global__ __launch_bounds__(256) void gcn_scatter(const int* __restrict__ src,
                                                   const int* __restrict__ dst,
                                                   const float* __restrict__ xw,
                                                   const float* __restrict__ dinv,
                                                   float* __restrict__ out) {
  int idx = blockIdx.x * 256 + threadIdx.x;   // NE*64
  int e = idx >> 6, c = idx & 63;
  int s = src[e], d = dst[e];
  atomicAdd(&out[d * 64 + c], xw[s * 64 + c] * dinv[s] * dinv[d]);
}

// ---------------------------------------------------------------- BatchNorm
// partial sums (coalesced) + atomics into stats[0..63]=sum, [64..127]=sumsq
__global__ __launch_bounds__(256) void bn_stats(const float* __restrict__ A,
                                                float* __restrict__ stats) {
  int t = threadIdx.x;
  int c = t & 63, rr = t >> 6;       // 4 row-lanes x 64 channels
  int r0 = blockIdx.x * 128;         // 64 blocks x 128 rows
  float s = 0.f, ss = 0.f;
  for (int i = rr; i < 128; i += 4) {
    float x = A[(r0 + i) * 64 + c];
    s += x; ss += x * x;
  }
  __shared__ float sb[4][64], ssb[4][64];
  sb[rr][c] = s; ssb[rr][c] = ss;
  __syncthreads();
  if (t < 64) {
    atomicAdd(&stats[t], sb[0][t] + sb[1][t] + sb[2][t] + sb[3][t]);
    atomicAdd(&stats[64 + t], ssb[0][t] + ssb[1][t] + ssb[2][t] + ssb[3][t]);
  }
}

__global__ __launch_bounds__(256) void bn_apply(float* __restrict__ A,
                                                const float* __restrict__ stats,
                                                const float* __restrict__ g,
                                                const float* __restrict__ b) {
  int idx = blockIdx.x * 256 + threadIdx.x;
  int c = idx & 63;
  float m = stats[c] * (1.f / NN);
  float v = stats[64 + c] * (1.f / NN) - m * m;
  A[idx] = (A[idx] - m) * rsqrtf(v + EPSV) * g[c] + b[c];
}

__global__ __launch_bounds__(256) void add_kernel(const float* __restrict__ a,
                                                  const float* __restrict__ b,
                                                  float* __restrict__ y) {
  int i = blockIdx.x * 256 + threadIdx.x;
  y[i] = a[i] + b[i];
}

// ------------------------------------------------------------ flash attention (fp32)
// BQ=32 query rows/block, BK=64 key tile. 256 threads: (ty 0..7, tx 0..31),
// thread owns rows ty*4+i (i<4), cols tx and tx+32 of the S/O tiles.
__global__ __launch_bounds__(256) void attn_flash(const float* __restrict__ Qg,
                                                  const float* __restrict__ Kg,
                                                  const float* __restrict__ Vg,
                                                  float* __restrict__ Og) {
  __shared__ float Qs[32][68];
  __shared__ float Ks[64][68];
  __shared__ float Vs[64][68];
  __shared__ float Ps[32][68];
  __shared__ float red[32][33];
  __shared__ float mrow[32], lrow[32], arow[32];

  const int t = threadIdx.x;
  const int qbase = blockIdx.x * 32;
  const int ty = t >> 5, tx = t & 31;

  for (int i = t; i < 32 * 64; i += 256)
    Qs[i >> 6][i & 63] = Qg[(qbase + (i >> 6)) * 64 + (i & 63)] * 0.125f;  // 1/sqrt(64)
  if (t < 32) { mrow[t] = -1e30f; lrow[t] = 0.f; }

  float Oa[4][2] = {};
  __syncthreads();

  for (int kb = 0; kb < NN; kb += 64) {
    for (int i = t; i < 64 * 64; i += 256) {
      int r = i >> 6, cc = i & 63;
      Ks[r][cc] = Kg[(kb + r) * 64 + cc];
      Vs[r][cc] = Vg[(kb + r) * 64 + cc];
    }
    __syncthreads();

    // S = Q @ K^T
    float s[4][2] = {};
#pragma unroll 2
    for (int kk = 0; kk < 64; kk += 4) {
      float a[4][4];
#pragma unroll
      for (int i = 0; i < 4; ++i) {
        float4 qv = *(const float4*)&Qs[ty * 4 + i][kk];
        a[i][0] = qv.x; a[i][1] = qv.y; a[i][2] = qv.z; a[i][3] = qv.w;
      }
      float4 k0 = *(const float4*)&Ks[tx][kk];
      float4 k1 = *(const float4*)&Ks[tx + 32][kk];
      float b0[4] = {k0.x, k0.y, k0.z, k0.w};
      float b1[4] = {k1.x, k1.y, k1.z, k1.w};
#pragma unroll
      for (int u = 0; u < 4; ++u)
#pragma unroll
        for (int i = 0; i < 4; ++i) {
          s[i][0] = fmaf(a[i][u], b0[u], s[i][0]);
          s[i][1] = fmaf(a[i][u], b1[u], s[i][1]);
        }
    }

    // tile row-max
#pragma unroll
    for (int i = 0; i < 4; ++i) red[ty * 4 + i][tx] = fmaxf(s[i][0], s[i][1]);
    __syncthreads();
    if (t < 32) {
      float mx = red[t][0];
#pragma unroll 8
      for (int j = 1; j < 32; ++j) mx = fmaxf(mx, red[t][j]);
      float mold = mrow[t];
      float mnew = fmaxf(mold, mx);
      arow[t] = __expf(mold - mnew);
      mrow[t] = mnew;
    }
    __syncthreads();

    // P = exp(S - m), partial row sums, rescale O accumulator
#pragma unroll
    for (int i = 0; i < 4; ++i) {
      int r = ty * 4 + i;
      float m = mrow[r];
      float p0 = __expf(s[i][0] - m);
      float p1 = __expf(s[i][1] - m);
      Ps[r][tx] = p0; Ps[r][tx + 32] = p1;
      red[r][tx] = p0 + p1;
    }
#pragma unroll
    for (int i = 0; i < 4; ++i) {
      float al = arow[ty * 4 + i];
      Oa[i][0] *= al; Oa[i][1] *= al;
    }
    __syncthreads();
    if (t < 32) {
      float sm = 0.f;
#pragma unroll 8
      for (int j = 0; j < 32; ++j) sm += red[t][j];
      lrow[t] = lrow[t] * arow[t] + sm;
    }

    // O += P @ V
#pragma unroll 2
    for (int kk = 0; kk < 64; kk += 4) {
      float p[4][4];
#pragma unroll
      for (int i = 0; i < 4; ++i) {
        float4 pv = *(const float4*)&Ps[ty * 4 + i][kk];
        p[i][0] = pv.x; p[i][1] = pv.y; p[i][2] = pv.z; p[i][3] = pv.w;
      }
#pragma unroll
      for (int u = 0; u < 4; ++u) {
        float v0 = Vs[kk + u][tx];
        float v1 = Vs[kk + u][tx + 32];
#pragma unroll
        for (int i = 0; i < 4; ++i) {
          Oa[i][0] = fmaf(p[i][u], v0, Oa[i][0]);
          Oa[i][1] = fmaf(p[i][u], v1, Oa[i][1]);
        }
      }
    }
    __syncthreads();
  }

#pragma unroll
  for (int i = 0; i < 4; ++i) {
    int r = ty * 4 + i;
    float inv = 1.f / lrow[r];
    Og[(qbase + r) * 64 + tx] = Oa[i][0] * inv;
    Og[(qbase + r) * 64 + tx + 32] = Oa[i][1] * inv;
  }
}

// ---------------------------------------------------------------- LayerNorm + ReLU
__global__ __launch_bounds__(256) void ln_relu(const float* __restrict__ A,
                                               const float* __restrict__ g,
                                               const float* __restrict__ b,
                                               float* __restrict__ H) {
  int w = threadIdx.x >> 6, lane = threadIdx.x & 63;
  int n = blockIdx.x * 4 + w;
  float x = A[n * 64 + lane];
  float s = x, ss = x * x;
  for (int o = 32; o > 0; o >>= 1) {
    s += __shfl_xor(s, o, 64);
    ss += __shfl_xor(ss, o, 64);
  }
  float m = s * (1.f / 64), v = ss * (1.f / 64) - m * m;
  float y = (x - m) * rsqrtf(v + EPSV) * g[lane] + b[lane];
  H[n * 64 + lane] = fmaxf(y, 0.f);
}

// ------------------------------------------- final GEMM (64x21) + log_softmax
__global__ __launch_bounds__(256) void final_kernel(const float* __restrict__ H,
                                                    const float* __restrict__ Wout,
                                                    const float* __restrict__ bout,
                                                    float* __restrict__ out) {
  int w = threadIdx.x >> 6, lane = threadIdx.x & 63;
  int n = blockIdx.x * 4 + w;
  const float* hr = H + n * 64;
  float acc = (lane < COUT) ? bout[lane] : -INFINITY;
  if (lane < COUT) {
#pragma unroll 16
    for (int k = 0; k < 64; ++k) acc = fmaf(hr[k], Wout[k * COUT + lane], acc);
  }
  float mx = acc;
  for (int o = 32; o > 0; o >>= 1) mx = fmaxf(mx, __shfl_xor(mx, o, 64));
  float e = __expf(acc - mx);
  float se = e;
  for (int o = 32; o > 0; o >>= 1) se += __shfl_xor(se, o, 64);
  float lse = mx + logf(se);
  if (lane < COUT) out[n * COUT + lane] = acc - lse;
}

// ================================================================ launch
extern "C" void kernel_launch(void* const* d_in, const int* in_sizes, int n_in,
                              void* d_out, int out_size, void* d_ws, size_t ws_size,
                              hipStream_t stream) {
  const float* x    = (const float*)d_in[0];
  const int*   ei   = (const int*)d_in[1];
  const float* W_in = (const float*)d_in[2];
  const float* b_in = (const float*)d_in[3];
  const float* gcnW = (const float*)d_in[4];
  const float* gcnB = (const float*)d_in[5];
  const float* Wqkv = (const float*)d_in[6];
  const float* bqkv = (const float*)d_in[7];
  const float* Wo   = (const float*)d_in[8];
  const float* bo   = (const float*)d_in[9];
  const float* bn1g = (const float*)d_in[10];
  const float* bn1b = (const float*)d_in[11];
  const float* bn2g = (const float*)d_in[12];
  const float* bn2b = (const float*)d_in[13];
  const float* bn3g = (const float*)d_in[14];
  const float* bn3b = (const float*)d_in[15];
  const float* W1   = (const float*)d_in[16];
  const float* b1   = (const float*)d_in[17];
  const float* W2   = (const float*)d_in[18];
  const float* b2   = (const float*)d_in[19];
  const float* lng  = (const float*)d_in[20];
  const float* lnb  = (const float*)d_in[21];
  const float* Wout = (const float*)d_in[22];
  const float* bout = (const float*)d_in[23];

  const int* src = ei;
  const int* dst = ei + NE;

  float* ws   = (float*)d_ws;
  float* h    = ws;              // N x 64
  float* t0   = h  + NN * C;     // N x 64
  float* t1   = t0 + NN * C;     // N x 64
  float* qb   = t1 + NN * C;
  float* kb   = qb + NN * C;
  float* vb   = kb + NN * C;
  float* t2   = vb + NN * C;
  float* t3   = t2 + NN * C;
  float* t4   = t3 + NN * C;
  float* m1   = t4 + NN * C;     // N x 128
  float* dinv = m1 + NN * CIN;   // N
  float* stats = dinv + NN;      // 128

  dim3 B(256);

  // degree / dinv (edge structure is fixed; recomputed every call for determinism)
  zero_f32<<<NN / 256, B, 0, stream>>>(dinv, NN);
  deg_kernel<<<NE / 256, B, 0, stream>>>(dst, dinv);
  dinv_kernel<<<NN / 256, B, 0, stream>>>(dinv);

  gemm_in_kernel<<<NN * C / 256, B, 0, stream>>>(x, W_in, b_in, h);

  for (int l = 0; l < NL; ++l) {
    // ---- local GCN branch: t1 = gcn(h) + b + h, then BN -> h1
    gemm_k<C, C, false, false, false, false><<<NN * C / 256, B, 0, stream>>>(h, gcnW + l * C * C, nullptr, nullptr, t0);
    gcn_init<<<NN * C / 256, B, 0, stream>>>(t0, h, gcnB + l * C, dinv, t1);
    gcn_scatter<<<NE * 64 / 256, B, 0, stream>>>(src, dst, t0, dinv, t1);
    zero_f32<<<1, 128, 0, stream>>>(stats, 128);
    bn_stats<<<64, B, 0, stream>>>(t1, stats);
    bn_apply<<<NN * C / 256, B, 0, stream>>>(t1, stats, bn1g + l * C, bn1b + l * C);

    // ---- global attention branch: t0 = attn(h)@Wo^T + bo + h, then BN -> h2
    qkv_kernel<<<NN * 192 / 256, B, 0, stream>>>(h, Wqkv + l * 192 * C, bqkv + l * 192, qb, kb, vb);
    attn_flash<<<NN / 32, B, 0, stream>>>(qb, kb, vb, t2);
    gemm_k<C, C, true, false, true, true><<<NN * C / 256, B, 0, stream>>>(t2, Wo + l * C * C, bo + l * C, h, t0);
    zero_f32<<<1, 128, 0, stream>>>(stats, 128);
    bn_stats<<<64, B, 0, stream>>>(t0, stats);
    bn_apply<<<NN * C / 256, B, 0, stream>>>(t0, stats, bn2g + l * C, bn2b + l * C);

    // ---- combine + MLP + BN -> t4, then LN+ReLU -> h
    add_kernel<<<NN * C / 256, B, 0, stream>>>(t1, t0, t3);
    gemm_k<C, 2 * C, false, true, false, true><<<NN * 2 * C / 256, B, 0, stream>>>(t3, W1 + l * C * 2 * C, b1 + l * 2 * C, nullptr, m1);
    gemm_k<2 * C, C, false, false, true, true><<<NN * C / 256, B, 0, stream>>>(m1, W2 + l * 2 * C * C, b2 + l * C, t3, t4);
    zero_f32<<<1, 128, 0, stream>>>(stats, 128);
    bn_stats<<<64, B, 0, stream>>>(t4, stats);
    bn_apply<<<NN * C / 256, B, 0, stream>>>(t4, stats, bn3g + l * C, bn3b + l * C);
    ln_relu<<<NN / 4, B, 0, stream>>>(t4, lng + l * C, lnb + l * C, h);
  }

  final_kernel<<<NN / 4, B, 0, stream>>>(h, Wout, bout, (float*)d_out);
}

// Round 2
// 1109.313 us; speedup vs baseline: 3.5690x; 3.5690x over previous
//
#include <hip/hip_runtime.h>
#include <math.h>

#define NN 8192
#define NE 131072
#define CIN 128
#define C 64
#define NL 4
#define COUT 21
#define EPSV 1e-5f

typedef unsigned short u16;
typedef __attribute__((ext_vector_type(8))) short short8;
typedef __attribute__((ext_vector_type(4))) float f32x4;

#define GAS __attribute__((address_space(1)))
#define LAS __attribute__((address_space(3)))

__device__ __forceinline__ void gload16(const void* g, void* l) {
  __builtin_amdgcn_global_load_lds((const GAS void*)g, (LAS void*)l, 16, 0, 0);
}

__device__ __forceinline__ u16 f2bf(float x) {
  unsigned int u = __float_as_uint(x);
  u += 0x7FFF + ((u >> 16) & 1);
  return (u16)(u >> 16);
}

// ---------------------------------------------------------------- utilities
__global__ void zero_f32(float* p, int n) {
  int i = blockIdx.x * blockDim.x + threadIdx.x;
  if (i < n) p[i] = 0.f;
}

__global__ void deg_kernel(const int* __restrict__ dst, float* __restrict__ deg) {
  int e = blockIdx.x * 256 + threadIdx.x;
  if (e < NE) atomicAdd(&deg[dst[e]], 1.0f);
}

__global__ void dinv_kernel(float* __restrict__ d) {
  int i = blockIdx.x * 256 + threadIdx.x;
  if (i < NN) d[i] = rsqrtf(d[i] + 1.0f);
}

// ------------------------------------------------------------- input GEMM
__global__ __launch_bounds__(256) void gemm_in_kernel(const float* __restrict__ X,
                                                      const float* __restrict__ W,
                                                      const float* __restrict__ b,
                                                      float* __restrict__ Y) {
  int idx = blockIdx.x * 256 + threadIdx.x;
  int n = idx >> 6, c = idx & 63;
  const float* xr = X + n * CIN;
  float acc = b[c];
#pragma unroll 16
  for (int k = 0; k < CIN; ++k) acc = fmaf(xr[k], W[k * C + c], acc);
  Y[idx] = acc;
}

// ------------------------------------------------- generic small GEMM
template <int K, int M, bool TB, bool RELU, bool RES, bool BIAS>
__global__ __launch_bounds__(256) void gemm_k(const float* __restrict__ X,
                                              const float* __restrict__ W,
                                              const float* __restrict__ bias,
                                              const float* __restrict__ res,
                                              float* __restrict__ Y) {
  int idx = blockIdx.x * 256 + threadIdx.x;
  int n = idx / M, m = idx % M;
  const float* xr = X + n * K;
  float acc = BIAS ? bias[m] : 0.f;
#pragma unroll 16
  for (int k = 0; k < K; ++k) acc = fmaf(xr[k], TB ? W[m * K + k] : W[k * M + m], acc);
  if (RES) acc += res[idx];
  if (RELU) acc = fmaxf(acc, 0.f);
  Y[idx] = acc;
}

// --------------------------------------------------------- QKV projection (bf16 out)
// Qb: [N][64] bf16, d-permuted, scaled by 0.125*log2(e). Kb: [N][64] bf16, d-permuted.
// Vt: [64][N] bf16 (d-major), key-index permuted within 32-groups.
// perm32(x): x = g*16+q*4+b  ->  p = q*8+g*4+b
__global__ __launch_bounds__(256) void qkv_kernel(const float* __restrict__ H,
                                                  const float* __restrict__ Wq,
                                                  const float* __restrict__ bq,
                                                  u16* __restrict__ Qb,
                                                  u16* __restrict__ Kb,
                                                  u16* __restrict__ Vt) {
  int idx = blockIdx.x * 256 + threadIdx.x;   // N*192
  int n = idx / 192, j = idx % 192;
  const float* xr = H + n * C;
  float acc = bq[j];
#pragma unroll 16
  for (int c = 0; c < C; ++c) acc = fmaf(xr[c], Wq[j * C + c], acc);
  int jj = j & 63;
  int pc = (jj & ~31) | (jj & 3) | (((jj >> 2) & 3) << 3) | (((jj >> 4) & 1) << 2);
  if (j < 64) {
    Qb[n * 64 + pc] = f2bf(acc * 0.18033688011112043f);  // 0.125 * log2(e)
  } else if (j < 128) {
    Kb[n * 64 + pc] = f2bf(acc);
  } else {
    int pn = (n & ~31) | (n & 3) | (((n >> 2) & 3) << 3) | (((n >> 4) & 1) << 2);
    Vt[(size_t)jj * NN + pn] = f2bf(acc);
  }
}

// ---------------------------------------------------------------- GCN
__global__ __launch_bounds__(256) void gcn_init(const float* __restrict__ xw,
                                                const float* __restrict__ h,
                                                const float* __restrict__ gb,
                                                const float* __restrict__ dinv,
                                                float* __restrict__ out) {
  int idx = blockIdx.x * 256 + threadIdx.x;
  int n = idx >> 6, c = idx & 63;
  float di = dinv[n];
  out[idx] = xw[idx] * di * di + gb[c] + h[idx];
}

__global__ __launch_bounds__(256) void gcn_scatter(const int* __restrict__ src,
                                                   const int* __restrict__ dst,
                                                   const float* __restrict__ xw,
                                                   const float* __restrict__ dinv,
                                                   float* __restrict__ out) {
  int idx = blockIdx.x * 256 + threadIdx.x;
  int e = idx >> 6, c = idx & 63;
  int s = src[e], d = dst[e];
  atomicAdd(&out[d * 64 + c], xw[s * 64 + c] * dinv[s] * dinv[d]);
}

// ---------------------------------------------------------------- BatchNorm
__global__ __launch_bounds__(256) void bn_stats(const float* __restrict__ A,
                                                float* __restrict__ stats) {
  int t = threadIdx.x;
  int c = t & 63, rr = t >> 6;
  int r0 = blockIdx.x * 128;
  float s = 0.f, ss = 0.f;
  for (int i = rr; i < 128; i += 4) {
    float x = A[(r0 + i) * 64 + c];
    s += x; ss += x * x;
  }
  __shared__ float sb[4][64], ssb[4][64];
  sb[rr][c] = s; ssb[rr][c] = ss;
  __syncthreads();
  if (t < 64) {
    atomicAdd(&stats[t], sb[0][t] + sb[1][t] + sb[2][t] + sb[3][t]);
    atomicAdd(&stats[64 + t], ssb[0][t] + ssb[1][t] + ssb[2][t] + ssb[3][t]);
  }
}

__global__ __launch_bounds__(256) void bn_apply(float* __restrict__ A,
                                                const float* __restrict__ stats,
                                                const float* __restrict__ g,
                                                const float* __restrict__ b) {
  int idx = blockIdx.x * 256 + threadIdx.x;
  int c = idx & 63;
  float m = stats[c] * (1.f / NN);
  float v = stats[64 + c] * (1.f / NN) - m * m;
  A[idx] = (A[idx] - m) * rsqrtf(v + EPSV) * g[c] + b[c];
}

__global__ __launch_bounds__(256) void add_kernel(const float* __restrict__ a,
                                                  const float* __restrict__ b,
                                                  float* __restrict__ y) {
  int i = blockIdx.x * 256 + threadIdx.x;
  y[i] = a[i] + b[i];
}

// ------------------------------------------------------------ MFMA flash attention
// 256 blocks x 256 threads. Block: Q rows [b*32, b*32+32). Wave w: KV range
// [w*2048, (w+1)*2048), 32 iters of 64 keys. Swapped QK^T (S^T = mfma(K,Q)),
// log2-domain online softmax, P feeds PV B-operand straight from registers.
// K/Vt staged per-wave via global_load_lds(16B), XOR-swizzled source, swizzled
// ds_read_b128. 4-way merge via LDS at the end.
__global__ __launch_bounds__(256, 1)
void attn_mfma(const u16* __restrict__ Qb, const u16* __restrict__ Kb,
               const u16* __restrict__ Vtb, float* __restrict__ Og) {
  __shared__ u16 smem[65536];  // 128 KiB: 2 bufs x 4 waves x {K,Vt} x 8KB
  const int tid = threadIdx.x;
  const int lane = tid & 63;
  const int w = tid >> 6;
  const int qbase = blockIdx.x * 32;
  const int kv0 = w * 2048;

  // Q fragments: [it][s], element e=(g*4+b) -> logical d = s*32+g*16+q*4+b,
  // matches permuted storage p = s*32+q*8+g*4+b with q = lane>>4.
  short8 qf[2][2];
#pragma unroll
  for (int it = 0; it < 2; ++it)
#pragma unroll
    for (int s = 0; s < 2; ++s)
      qf[it][s] = *(const short8*)(Qb + (size_t)(qbase + it * 16 + (lane & 15)) * 64 +
                                   s * 32 + (lane >> 4) * 8);

  f32x4 o[4][2] = {};          // O^T tiles [dt][it]
  float m[2] = {-3.0e38f, -3.0e38f};
  float ll[2] = {0.f, 0.f};

  const int r8 = lane >> 3;
  const int scb = ((lane & 7) * 16) ^ (r8 << 4);  // staging src colbyte (swizzled)

  auto stage = [&](int buf, int ch) {
    const int kvs = kv0 + ch * 64;
    char* kdst = (char*)(smem + (((buf * 4 + w) * 2 + 0) << 12));
    char* vdst = (char*)(smem + (((buf * 4 + w) * 2 + 1) << 12));
    const char* kS = (const char*)Kb + (size_t)(kvs + r8) * 128 + scb;
    const char* vS = (const char*)Vtb + (size_t)r8 * (NN * 2) + (size_t)kvs * 2 + scb;
#pragma unroll
    for (int i = 0; i < 8; ++i) {
      gload16(kS + i * 1024, kdst + i * 1024);
      gload16(vS + (size_t)i * 8 * (NN * 2), vdst + i * 1024);
    }
  };

  int cb = 0;
  stage(0, 0);
  for (int t = 0; t < 32; ++t) {
    if (t < 31) stage(cb ^ 1, t + 1);
    __builtin_amdgcn_sched_barrier(0);
    if (t < 31) asm volatile("s_waitcnt vmcnt(16)" ::: "memory");
    else        asm volatile("s_waitcnt vmcnt(0)" ::: "memory");
    __builtin_amdgcn_sched_barrier(0);

    const char* kt = (const char*)(smem + (((cb * 4 + w) * 2 + 0) << 12));
    const char* vt = (const char*)(smem + (((cb * 4 + w) * 2 + 1) << 12));
    const int rb = (lane & 15) * 128;

    // ---- S^T = K @ Q^T   (tiles st[jt][it])
    f32x4 st[4][2] = {};
#pragma unroll
    for (int s = 0; s < 2; ++s) {
      const int colx = (((s << 2) + (lane >> 4)) ^ (lane & 7)) << 4;
#pragma unroll
      for (int jt = 0; jt < 4; ++jt) {
        short8 kf = *(const short8*)(kt + jt * 2048 + rb + colx);
#pragma unroll
        for (int it = 0; it < 2; ++it)
          st[jt][it] = __builtin_amdgcn_mfma_f32_16x16x32_bf16(kf, qf[it][s], st[jt][it], 0, 0, 0);
      }
    }

    // ---- online softmax (log2 domain), pack P to bf16 frags pf[s][it]
    short8 pf[2][2];
#pragma unroll
    for (int it = 0; it < 2; ++it) {
      float mx = -3.0e38f;
#pragma unroll
      for (int jt = 0; jt < 4; ++jt)
#pragma unroll
        for (int r = 0; r < 4; ++r) mx = fmaxf(mx, st[jt][it][r]);
      mx = fmaxf(mx, __shfl_xor(mx, 16));
      mx = fmaxf(mx, __shfl_xor(mx, 32));
      float mn = fmaxf(m[it], mx);
      float sc = exp2f(m[it] - mn);
      m[it] = mn;
      float ps = 0.f;
#pragma unroll
      for (int jt = 0; jt < 4; ++jt)
#pragma unroll
        for (int r = 0; r < 4; ++r) {
          float p = exp2f(st[jt][it][r] - mn);
          ps += p;
          unsigned int u = __float_as_uint(p);
          u += 0x7FFF + ((u >> 16) & 1);
          pf[jt >> 1][it][(jt & 1) * 4 + r] = (short)(u >> 16);
        }
      ps += __shfl_xor(ps, 16);
      ps += __shfl_xor(ps, 32);
      ll[it] = ll[it] * sc + ps;
#pragma unroll
      for (int dt = 0; dt < 4; ++dt) o[dt][it] *= sc;
    }

    // ---- O^T += V^T @ P^T
#pragma unroll
    for (int s = 0; s < 2; ++s) {
      const int colx = (((s << 2) + (lane >> 4)) ^ (lane & 7)) << 4;
#pragma unroll
      for (int dt = 0; dt < 4; ++dt) {
        short8 vf = *(const short8*)(vt + dt * 2048 + rb + colx);
#pragma unroll
        for (int it = 0; it < 2; ++it)
          o[dt][it] = __builtin_amdgcn_mfma_f32_16x16x32_bf16(vf, pf[s][it], o[dt][it], 0, 0, 0);
      }
    }
    cb ^= 1;
  }

  // ---- 4-way KV merge via LDS
  __syncthreads();
  float* fsm = (float*)smem;
#pragma unroll
  for (int dt = 0; dt < 4; ++dt)
#pragma unroll
    for (int it = 0; it < 2; ++it) {
      int d0 = dt * 16 + ((lane >> 4) << 2);
      int i = it * 16 + (lane & 15);
      *(f32x4*)&fsm[w * 2048 + i * 64 + d0] = o[dt][it];
    }
  if (lane < 16) {
#pragma unroll
    for (int it = 0; it < 2; ++it) {
      fsm[8192 + (w * 2 + it) * 16 + lane] = m[it];
      fsm[8320 + (w * 2 + it) * 16 + lane] = ll[it];
    }
  }
  __syncthreads();

  const int i = tid & 31, seg = tid >> 5;
  const int itm = i >> 4, ii = i & 15;
  float mw[4], lw[4], sw[4];
  float M = -3.0e38f;
#pragma unroll
  for (int u2 = 0; u2 < 4; ++u2) {
    mw[u2] = fsm[8192 + (u2 * 2 + itm) * 16 + ii];
    lw[u2] = fsm[8320 + (u2 * 2 + itm) * 16 + ii];
    M = fmaxf(M, mw[u2]);
  }
  float den = 0.f;
#pragma unroll
  for (int u2 = 0; u2 < 4; ++u2) { sw[u2] = exp2f(mw[u2] - M); den += sw[u2] * lw[u2]; }
  float inv = 1.f / den;
#pragma unroll
  for (int dd = 0; dd < 8; ++dd) {
    int d = seg * 8 + dd;
    float num = 0.f;
#pragma unroll
    for (int u2 = 0; u2 < 4; ++u2) num += sw[u2] * fsm[u2 * 2048 + i * 64 + d];
    Og[(size_t)(qbase + i) * 64 + d] = num * inv;
  }
}

// ---------------------------------------------------------------- LayerNorm + ReLU
__global__ __launch_bounds__(256) void ln_relu(const float* __restrict__ A,
                                               const float* __restrict__ g,
                                               const float* __restrict__ b,
                                               float* __restrict__ H) {
  int w = threadIdx.x >> 6, lane = threadIdx.x & 63;
  int n = blockIdx.x * 4 + w;
  float x = A[n * 64 + lane];
  float s = x, ss = x * x;
  for (int o = 32; o > 0; o >>= 1) {
    s += __shfl_xor(s, o, 64);
    ss += __shfl_xor(ss, o, 64);
  }
  float m = s * (1.f / 64), v = ss * (1.f / 64) - m * m;
  float y = (x - m) * rsqrtf(v + EPSV) * g[lane] + b[lane];
  H[n * 64 + lane] = fmaxf(y, 0.f);
}

// ------------------------------------------- final GEMM (64x21) + log_softmax
__global__ __launch_bounds__(256) void final_kernel(const float* __restrict__ H,
                                                    const float* __restrict__ Wout,
                                                    const float* __restrict__ bout,
                                                    float* __restrict__ out) {
  int w = threadIdx.x >> 6, lane = threadIdx.x & 63;
  int n = blockIdx.x * 4 + w;
  const float* hr = H + n * 64;
  float acc = (lane < COUT) ? bout[lane] : -INFINITY;
  if (lane < COUT) {
#pragma unroll 16
    for (int k = 0; k < 64; ++k) acc = fmaf(hr[k], Wout[k * COUT + lane], acc);
  }
  float mx = acc;
  for (int o = 32; o > 0; o >>= 1) mx = fmaxf(mx, __shfl_xor(mx, o, 64));
  float e = __expf(acc - mx);
  float se = e;
  for (int o = 32; o > 0; o >>= 1) se += __shfl_xor(se, o, 64);
  float lse = mx + logf(se);
  if (lane < COUT) out[n * COUT + lane] = acc - lse;
}

// ================================================================ launch
extern "C" void kernel_launch(void* const* d_in, const int* in_sizes, int n_in,
                              void* d_out, int out_size, void* d_ws, size_t ws_size,
                              hipStream_t stream) {
  const float* x    = (const float*)d_in[0];
  const int*   ei   = (const int*)d_in[1];
  const float* W_in = (const float*)d_in[2];
  const float* b_in = (const float*)d_in[3];
  const float* gcnW = (const float*)d_in[4];
  const float* gcnB = (const float*)d_in[5];
  const float* Wqkv = (const float*)d_in[6];
  const float* bqkv = (const float*)d_in[7];
  const float* Wo   = (const float*)d_in[8];
  const float* bo   = (const float*)d_in[9];
  const float* bn1g = (const float*)d_in[10];
  const float* bn1b = (const float*)d_in[11];
  const float* bn2g = (const float*)d_in[12];
  const float* bn2b = (const float*)d_in[13];
  const float* bn3g = (const float*)d_in[14];
  const float* bn3b = (const float*)d_in[15];
  const float* W1   = (const float*)d_in[16];
  const float* b1   = (const float*)d_in[17];
  const float* W2   = (const float*)d_in[18];
  const float* b2   = (const float*)d_in[19];
  const float* lng  = (const float*)d_in[20];
  const float* lnb  = (const float*)d_in[21];
  const float* Wout = (const float*)d_in[22];
  const float* bout = (const float*)d_in[23];

  const int* src = ei;
  const int* dst = ei + NE;

  float* ws    = (float*)d_ws;
  float* h     = ws;
  float* t0    = h  + NN * C;
  float* t1    = t0 + NN * C;
  float* t2    = t1 + NN * C;
  float* t3    = t2 + NN * C;
  float* t4    = t3 + NN * C;
  float* m1    = t4 + NN * C;     // N x 128
  float* dinv  = m1 + NN * CIN;   // N
  float* stats = dinv + NN;       // 128
  u16*  Qb  = (u16*)(stats + 128);
  u16*  Kb  = Qb + NN * 64;
  u16*  Vtb = Kb + NN * 64;

  dim3 B(256);

  zero_f32<<<NN / 256, B, 0, stream>>>(dinv, NN);
  deg_kernel<<<NE / 256, B, 0, stream>>>(dst, dinv);
  dinv_kernel<<<NN / 256, B, 0, stream>>>(dinv);

  gemm_in_kernel<<<NN * C / 256, B, 0, stream>>>(x, W_in, b_in, h);

  for (int l = 0; l < NL; ++l) {
    // ---- local GCN branch + residual + BN -> t1
    gemm_k<C, C, false, false, false, false><<<NN * C / 256, B, 0, stream>>>(h, gcnW + l * C * C, nullptr, nullptr, t0);
    gcn_init<<<NN * C / 256, B, 0, stream>>>(t0, h, gcnB + l * C, dinv, t1);
    gcn_scatter<<<NE * 64 / 256, B, 0, stream>>>(src, dst, t0, dinv, t1);
    zero_f32<<<1, 128, 0, stream>>>(stats, 128);
    bn_stats<<<64, B, 0, stream>>>(t1, stats);
    bn_apply<<<NN * C / 256, B, 0, stream>>>(t1, stats, bn1g + l * C, bn1b + l * C);

    // ---- global attention branch + residual + BN -> t0
    qkv_kernel<<<NN * 192 / 256, B, 0, stream>>>(h, Wqkv + l * 192 * C, bqkv + l * 192, Qb, Kb, Vtb);
    attn_mfma<<<256, B, 0, stream>>>(Qb, Kb, Vtb, t2);
    gemm_k<C, C, true, false, true, true><<<NN * C / 256, B, 0, stream>>>(t2, Wo + l * C * C, bo + l * C, h, t0);
    zero_f32<<<1, 128, 0, stream>>>(stats, 128);
    bn_stats<<<64, B, 0, stream>>>(t0, stats);
    bn_apply<<<NN * C / 256, B, 0, stream>>>(t0, stats, bn2g + l * C, bn2b + l * C);

    // ---- combine + MLP + BN -> t4, then LN+ReLU -> h
    add_kernel<<<NN * C / 256, B, 0, stream>>>(t1, t0, t3);
    gemm_k<C, 2 * C, false, true, false, true><<<NN * 2 * C / 256, B, 0, stream>>>(t3, W1 + l * C * 2 * C, b1 + l * 2 * C, nullptr, m1);
    gemm_k<2 * C, C, false, false, true, true><<<NN * C / 256, B, 0, stream>>>(m1, W2 + l * 2 * C * C, b2 + l * C, t3, t4);
    zero_f32<<<1, 128, 0, stream>>>(stats, 128);
    bn_stats<<<64, B, 0, stream>>>(t4, stats);
    bn_apply<<<NN * C / 256, B, 0, stream>>>(t4, stats, bn3g + l * C, bn3b + l * C);
    ln_relu<<<NN / 4, B, 0, stream>>>(t4, lng + l * C, lnb + l * C, h);
  }

  final_kernel<<<NN / 4, B, 0, stream>>>(h, Wout, bout, (float*)d_out);
}

// Round 3
// 952.253 us; speedup vs baseline: 4.1577x; 1.1649x over previous
//
#include <hip/hip_runtime.h>
#include <math.h>

#define NN 8192
#define NE 131072
#define CIN 128
#define C 64
#define NL 4
#define COUT 21
#define EPSV 1e-5f

typedef unsigned short u16;
typedef __attribute__((ext_vector_type(8))) short short8;
typedef __attribute__((ext_vector_type(4))) float f32x4;
typedef __attribute__((ext_vector_type(4))) unsigned int u32x4;

__device__ __forceinline__ u16 f2bf(float x) {
  unsigned int u = __float_as_uint(x);
  u += 0x7FFF + ((u >> 16) & 1);
  return (u16)(u >> 16);
}

__device__ __forceinline__ unsigned cvtpk(float a, float b) {
  unsigned r;
  asm("v_cvt_pk_bf16_f32 %0, %1, %2" : "=v"(r) : "v"(a), "v"(b));
  return r;
}

// ---------------------------------------------------------------- setup
__global__ void zero_setup(float* __restrict__ stats, int* __restrict__ degi) {
  int i = blockIdx.x * 256 + threadIdx.x;
  if (i < 1536) stats[i] = 0.f;
  if (i < NN) degi[i] = 0;
}

__global__ void deg_kernel(const int* __restrict__ dst, int* __restrict__ degi) {
  int e = blockIdx.x * 256 + threadIdx.x;
  if (e < NE) atomicAdd(&degi[dst[e]], 1);
}

__global__ __launch_bounds__(256) void prefix_kernel(const int* __restrict__ degi,
                                                     int* __restrict__ rowptr,
                                                     int* __restrict__ cursor) {
  __shared__ int part[256];
  int t = threadIdx.x;
  int base = t * 32;
  int loc[32];
  int s = 0;
#pragma unroll
  for (int i = 0; i < 32; ++i) { loc[i] = s; s += degi[base + i]; }
  part[t] = s;
  __syncthreads();
  for (int off = 1; off < 256; off <<= 1) {
    int v = (t >= off) ? part[t - off] : 0;
    __syncthreads();
    part[t] += v;
    __syncthreads();
  }
  int chunkbase = (t == 0) ? 0 : part[t - 1];
#pragma unroll
  for (int i = 0; i < 32; ++i) {
    int v = chunkbase + loc[i];
    rowptr[base + i] = v;
    cursor[base + i] = v;
  }
  if (t == 255) rowptr[NN] = part[255];
}

__global__ void dinv_kernel(const int* __restrict__ degi, float* __restrict__ dinv) {
  int i = blockIdx.x * 256 + threadIdx.x;
  if (i < NN) dinv[i] = rsqrtf((float)degi[i] + 1.0f);
}

__global__ void fill_kernel(const int* __restrict__ src, const int* __restrict__ dst,
                            int* __restrict__ cursor, int* __restrict__ esrc) {
  int e = blockIdx.x * 256 + threadIdx.x;
  if (e < NE) {
    int d = dst[e];
    int pos = atomicAdd(&cursor[d], 1);
    esrc[pos] = src[e];
  }
}

// ------------------------------------------------------------- input GEMM
__global__ __launch_bounds__(256) void gemm_in_kernel(const float* __restrict__ X,
                                                      const float* __restrict__ W,
                                                      const float* __restrict__ b,
                                                      float* __restrict__ Y) {
  int idx = blockIdx.x * 256 + threadIdx.x;
  int n = idx >> 6, c = idx & 63;
  const float* xr = X + n * CIN;
  float acc = b[c];
#pragma unroll 16
  for (int k = 0; k < CIN; ++k) acc = fmaf(xr[k], W[k * C + c], acc);
  Y[idx] = acc;
}

// --------------------------------------------- GCN gemm + self-loop init (fused)
__global__ __launch_bounds__(256) void gcn_gemm_init(const float* __restrict__ H,
                                                     const float* __restrict__ Wg,
                                                     const float* __restrict__ gb,
                                                     const float* __restrict__ dinv,
                                                     float* __restrict__ xw,
                                                     float* __restrict__ t1) {
  int idx = blockIdx.x * 256 + threadIdx.x;
  int n = idx >> 6, c = idx & 63;
  const float* xr = H + n * 64;
  float acc = 0.f;
#pragma unroll 16
  for (int k = 0; k < 64; ++k) acc = fmaf(xr[k], Wg[k * 64 + c], acc);
  xw[idx] = acc;
  float di = dinv[n];
  t1[idx] = acc * di * di + gb[c] + H[idx];
}

// --------------------------------------------- GCN gather (CSR, no atomics)
__global__ __launch_bounds__(256) void gcn_gather(const int* __restrict__ rowptr,
                                                  const int* __restrict__ esrc,
                                                  const float* __restrict__ xw,
                                                  const float* __restrict__ dinv,
                                                  float* __restrict__ t1) {
  int w = threadIdx.x >> 6, lane = threadIdx.x & 63;
  int d = blockIdx.x * 4 + w;
  int beg = rowptr[d], end = rowptr[d + 1];
  float acc = 0.f;
  for (int i = beg; i < end; ++i) {
    int s = esrc[i];
    acc = fmaf(xw[s * 64 + lane], dinv[s], acc);
  }
  int idx = d * 64 + lane;
  t1[idx] = t1[idx] + acc * dinv[d];
}

// ---------------------------------------------------------------- BN stats
__global__ __launch_bounds__(256) void bn_stats(const float* __restrict__ A,
                                                float* __restrict__ stats) {
  int t = threadIdx.x;
  int c = t & 63, rr = t >> 6;
  int r0 = blockIdx.x * 32;
  float s = 0.f, ss = 0.f;
  for (int i = rr; i < 32; i += 4) {
    float x = A[(r0 + i) * 64 + c];
    s += x; ss += x * x;
  }
  __shared__ float sb[4][64], ssb[4][64];
  sb[rr][c] = s; ssb[rr][c] = ss;
  __syncthreads();
  if (t < 64) {
    atomicAdd(&stats[t], sb[0][t] + sb[1][t] + sb[2][t] + sb[3][t]);
    atomicAdd(&stats[64 + t], ssb[0][t] + ssb[1][t] + ssb[2][t] + ssb[3][t]);
  }
}

// ------------------------------------------- bn1(t1) + bn2(t0) -> t3 (fused)
__global__ __launch_bounds__(256) void combine_kernel(const float* __restrict__ t1,
                                                      const float* __restrict__ t0,
                                                      const float* __restrict__ s1,
                                                      const float* __restrict__ s2,
                                                      const float* __restrict__ g1,
                                                      const float* __restrict__ b1,
                                                      const float* __restrict__ g2,
                                                      const float* __restrict__ b2,
                                                      float* __restrict__ t3) {
  int idx = blockIdx.x * 256 + threadIdx.x;
  int c = idx & 63;
  float m1 = s1[c] * (1.f / NN);
  float v1 = s1[64 + c] * (1.f / NN) - m1 * m1;
  float m2 = s2[c] * (1.f / NN);
  float v2 = s2[64 + c] * (1.f / NN) - m2 * m2;
  t3[idx] = (t1[idx] - m1) * rsqrtf(v1 + EPSV) * g1[c] + b1[c] +
            (t0[idx] - m2) * rsqrtf(v2 + EPSV) * g2[c] + b2[c];
}

// --------------------------------------------------------- QKV projection (bf16 out)
__global__ __launch_bounds__(256) void qkv_kernel(const float* __restrict__ H,
                                                  const float* __restrict__ Wq,
                                                  const float* __restrict__ bq,
                                                  u16* __restrict__ Qb,
                                                  u16* __restrict__ Kb,
                                                  u16* __restrict__ Vt) {
  int idx = blockIdx.x * 256 + threadIdx.x;   // N*192
  int n = idx / 192, j = idx % 192;
  const float* xr = H + n * C;
  float acc = bq[j];
#pragma unroll 16
  for (int c = 0; c < C; ++c) acc = fmaf(xr[c], Wq[j * C + c], acc);
  int jj = j & 63;
  int pc = (jj & ~31) | (jj & 3) | (((jj >> 2) & 3) << 3) | (((jj >> 4) & 1) << 2);
  if (j < 64) {
    Qb[n * 64 + pc] = f2bf(acc * 0.18033688011112043f);  // 0.125 * log2(e)
  } else if (j < 128) {
    Kb[n * 64 + pc] = f2bf(acc);
  } else {
    int pn = (n & ~31) | (n & 3) | (((n >> 2) & 3) << 3) | (((n >> 4) & 1) << 2);
    Vt[(size_t)jj * NN + pn] = f2bf(acc);
  }
}

// ------------------------------------------------------------ MFMA flash attention
// grid 256 x 512 threads. Block: Q rows [b*32, +32). Wave w (0..7): keys
// [w*1024, +1024) = 16 tiles of 64. K/V fragments loaded straight from global
// (L2-resident) into registers; fixed-max softmax (scores pre-scaled to log2
// domain and provably tiny); P packed via v_cvt_pk_bf16_f32; 8-way merge in LDS.
__device__ __forceinline__ void attn_tile(const u16* __restrict__ kb,
                                          const u16* __restrict__ vb,
                                          int koff, int voff,
                                          const short8 (&qf)[2][2],
                                          f32x4 (&o)[4][2], float (&ll)[2]) {
  short8 kf[8];
#pragma unroll
  for (int jt = 0; jt < 4; ++jt)
#pragma unroll
    for (int s = 0; s < 2; ++s)
      kf[jt * 2 + s] = *(const short8*)(kb + koff + jt * 1024 + s * 32);
  short8 vf[8];
#pragma unroll
  for (int dt = 0; dt < 4; ++dt)
#pragma unroll
    for (int s = 0; s < 2; ++s)
      vf[dt * 2 + s] = *(const short8*)(vb + voff + dt * 16 * NN + s * 32);

  f32x4 st[4][2] = {};
#pragma unroll
  for (int s = 0; s < 2; ++s)
#pragma unroll
    for (int jt = 0; jt < 4; ++jt)
#pragma unroll
      for (int it = 0; it < 2; ++it)
        st[jt][it] = __builtin_amdgcn_mfma_f32_16x16x32_bf16(kf[jt * 2 + s], qf[it][s],
                                                             st[jt][it], 0, 0, 0);
  short8 pf[2][2];
#pragma unroll
  for (int it = 0; it < 2; ++it) {
    float p[4][4];
    float ps = 0.f;
#pragma unroll
    for (int jt = 0; jt < 4; ++jt) {
#pragma unroll
      for (int rr = 0; rr < 4; ++rr) p[jt][rr] = exp2f(st[jt][it][rr]);
      ps += (p[jt][0] + p[jt][1]) + (p[jt][2] + p[jt][3]);
    }
    ps += __shfl_xor(ps, 16);
    ps += __shfl_xor(ps, 32);
    ll[it] += ps;
    u32x4 a0, a1;
    a0[0] = cvtpk(p[0][0], p[0][1]); a0[1] = cvtpk(p[0][2], p[0][3]);
    a0[2] = cvtpk(p[1][0], p[1][1]); a0[3] = cvtpk(p[1][2], p[1][3]);
    a1[0] = cvtpk(p[2][0], p[2][1]); a1[1] = cvtpk(p[2][2], p[2][3]);
    a1[2] = cvtpk(p[3][0], p[3][1]); a1[3] = cvtpk(p[3][2], p[3][3]);
    pf[0][it] = __builtin_bit_cast(short8, a0);
    pf[1][it] = __builtin_bit_cast(short8, a1);
  }
#pragma unroll
  for (int s = 0; s < 2; ++s)
#pragma unroll
    for (int dt = 0; dt < 4; ++dt)
#pragma unroll
      for (int it = 0; it < 2; ++it)
        o[dt][it] = __builtin_amdgcn_mfma_f32_16x16x32_bf16(vf[dt * 2 + s], pf[s][it],
                                                            o[dt][it], 0, 0, 0);
}

__global__ __launch_bounds__(512, 2)
void attn_mfma(const u16* __restrict__ Qb, const u16* __restrict__ Kb,
               const u16* __restrict__ Vtb, float* __restrict__ Og) {
  __shared__ float fsm[4 * 32 * 68 + 8 * 32];
  float* llb = fsm + 4 * 32 * 68;
  const int tid = threadIdx.x;
  const int lane = tid & 63;
  const int w = tid >> 6;
  const int qbase = blockIdx.x * 32;
  const int kv0 = w * 1024;
  const int r = lane & 15, q = lane >> 4;

  short8 qf[2][2];
#pragma unroll
  for (int it = 0; it < 2; ++it)
#pragma unroll
    for (int s = 0; s < 2; ++s)
      qf[it][s] = *(const short8*)(Qb + (size_t)(qbase + it * 16 + r) * 64 + s * 32 + q * 8);

  f32x4 o[4][2] = {};
  float ll[2] = {0.f, 0.f};

  const u16* kb = Kb + (size_t)(kv0 + r) * 64 + q * 8;
  const u16* vb = Vtb + (size_t)r * NN + kv0 + q * 8;

#pragma unroll 1
  for (int t = 0; t < 16; ++t)
    attn_tile(kb, vb, t * 4096, t * 64, qf, o, ll);

  // ---- 8-way merge
  if (w < 4) {
#pragma unroll
    for (int dt = 0; dt < 4; ++dt)
#pragma unroll
      for (int it = 0; it < 2; ++it)
        *(f32x4*)&fsm[w * (32 * 68) + (it * 16 + r) * 68 + dt * 16 + q * 4] = o[dt][it];
  }
  if (lane < 16) {
    llb[w * 32 + lane] = ll[0];
    llb[w * 32 + 16 + lane] = ll[1];
  }
  __syncthreads();
  if (w >= 4) {
#pragma unroll
    for (int dt = 0; dt < 4; ++dt)
#pragma unroll
      for (int it = 0; it < 2; ++it) {
        float* p = &fsm[(w - 4) * (32 * 68) + (it * 16 + r) * 68 + dt * 16 + q * 4];
        *(f32x4*)p = *(const f32x4*)p + o[dt][it];
      }
  }
  __syncthreads();
  int i = tid >> 4, c0 = (tid & 15) * 4;
  float den = 0.f;
#pragma unroll
  for (int u2 = 0; u2 < 8; ++u2) den += llb[u2 * 32 + i];
  f32x4 num = {};
#pragma unroll
  for (int u2 = 0; u2 < 4; ++u2) num += *(const f32x4*)&fsm[u2 * (32 * 68) + i * 68 + c0];
  float inv = 1.f / den;
  *(f32x4*)&Og[(size_t)(qbase + i) * 64 + c0] = num * inv;
}

// ------------------------------------------------- O-projection (+res +bias)
__global__ __launch_bounds__(256) void oproj_kernel(const float* __restrict__ X,
                                                    const float* __restrict__ W,
                                                    const float* __restrict__ bias,
                                                    const float* __restrict__ res,
                                                    float* __restrict__ Y) {
  int idx = blockIdx.x * 256 + threadIdx.x;
  int n = idx >> 6, m = idx & 63;
  const float* xr = X + n * 64;
  float acc = bias[m];
#pragma unroll 16
  for (int k = 0; k < 64; ++k) acc = fmaf(xr[k], W[m * 64 + k], acc);
  Y[idx] = acc + res[idx];
}

// ------------------------------------------------- fused MLP (+relu +residual)
__global__ __launch_bounds__(256) void mlp_kernel(const float* __restrict__ t3,
                                                  const float* __restrict__ W1,
                                                  const float* __restrict__ b1,
                                                  const float* __restrict__ W2,
                                                  const float* __restrict__ b2,
                                                  float* __restrict__ t4) {
  __shared__ float rows[32][68];
  __shared__ float mid[32][132];
  int t = threadIdx.x;
  int r0 = blockIdx.x * 32;
  for (int i = t; i < 2048; i += 256)
    rows[i >> 6][i & 63] = t3[(r0 + (i >> 6)) * 64 + (i & 63)];
  __syncthreads();
  int r = t >> 3;
  {
    int m0 = (t & 7) * 16;
    float acc[16];
#pragma unroll
    for (int j = 0; j < 16; ++j) acc[j] = b1[m0 + j];
    for (int k = 0; k < 64; ++k) {
      float xv = rows[r][k];
#pragma unroll
      for (int j = 0; j < 16; ++j) acc[j] = fmaf(xv, W1[k * 128 + m0 + j], acc[j]);
    }
#pragma unroll
    for (int j = 0; j < 16; ++j) mid[r][m0 + j] = fmaxf(acc[j], 0.f);
  }
  __syncthreads();
  {
    int c0 = (t & 7) * 8;
    float oc[8];
#pragma unroll
    for (int j = 0; j < 8; ++j) oc[j] = b2[c0 + j] + rows[r][c0 + j];
    for (int k = 0; k < 128; ++k) {
      float mv = mid[r][k];
#pragma unroll
      for (int j = 0; j < 8; ++j) oc[j] = fmaf(mv, W2[k * 64 + c0 + j], oc[j]);
    }
#pragma unroll
    for (int j = 0; j < 8; ++j) t4[(r0 + r) * 64 + c0 + j] = oc[j];
  }
}

// ------------------------------------------- BN3 + LayerNorm + ReLU (fused)
__global__ __launch_bounds__(256) void bn3_ln_relu(const float* __restrict__ t4,
                                                   const float* __restrict__ s3,
                                                   const float* __restrict__ g3,
                                                   const float* __restrict__ b3,
                                                   const float* __restrict__ lg,
                                                   const float* __restrict__ lb,
                                                   float* __restrict__ H) {
  int wv = threadIdx.x >> 6, lane = threadIdx.x & 63;
  int n = blockIdx.x * 4 + wv;
  float m3 = s3[lane] * (1.f / NN);
  float v3 = s3[64 + lane] * (1.f / NN) - m3 * m3;
  float x = (t4[n * 64 + lane] - m3) * rsqrtf(v3 + EPSV) * g3[lane] + b3[lane];
  float s = x, ss = x * x;
  for (int o = 32; o > 0; o >>= 1) {
    s += __shfl_xor(s, o, 64);
    ss += __shfl_xor(ss, o, 64);
  }
  float m = s * (1.f / 64), v = ss * (1.f / 64) - m * m;
  float y = (x - m) * rsqrtf(v + EPSV) * lg[lane] + lb[lane];
  H[n * 64 + lane] = fmaxf(y, 0.f);
}

// ------------------------------------------- final GEMM (64x21) + log_softmax
__global__ __launch_bounds__(256) void final_kernel(const float* __restrict__ H,
                                                    const float* __restrict__ Wout,
                                                    const float* __restrict__ bout,
                                                    float* __restrict__ out) {
  int w = threadIdx.x >> 6, lane = threadIdx.x & 63;
  int n = blockIdx.x * 4 + w;
  const float* hr = H + n * 64;
  float acc = (lane < COUT) ? bout[lane] : -INFINITY;
  if (lane < COUT) {
#pragma unroll 16
    for (int k = 0; k < 64; ++k) acc = fmaf(hr[k], Wout[k * COUT + lane], acc);
  }
  float mx = acc;
  for (int o = 32; o > 0; o >>= 1) mx = fmaxf(mx, __shfl_xor(mx, o, 64));
  float e = __expf(acc - mx);
  float se = e;
  for (int o = 32; o > 0; o >>= 1) se += __shfl_xor(se, o, 64);
  float lse = mx + logf(se);
  if (lane < COUT) out[n * COUT + lane] = acc - lse;
}

// ================================================================ launch
extern "C" void kernel_launch(void* const* d_in, const int* in_sizes, int n_in,
                              void* d_out, int out_size, void* d_ws, size_t ws_size,
                              hipStream_t stream) {
  const float* x    = (const float*)d_in[0];
  const int*   ei   = (const int*)d_in[1];
  const float* W_in = (const float*)d_in[2];
  const float* b_in = (const float*)d_in[3];
  const float* gcnW = (const float*)d_in[4];
  const float* gcnB = (const float*)d_in[5];
  const float* Wqkv = (const float*)d_in[6];
  const float* bqkv = (const float*)d_in[7];
  const float* Wo   = (const float*)d_in[8];
  const float* bo   = (const float*)d_in[9];
  const float* bn1g = (const float*)d_in[10];
  const float* bn1b = (const float*)d_in[11];
  const float* bn2g = (const float*)d_in[12];
  const float* bn2b = (const float*)d_in[13];
  const float* bn3g = (const float*)d_in[14];
  const float* bn3b = (const float*)d_in[15];
  const float* W1   = (const float*)d_in[16];
  const float* b1   = (const float*)d_in[17];
  const float* W2   = (const float*)d_in[18];
  const float* b2   = (const float*)d_in[19];
  const float* lng  = (const float*)d_in[20];
  const float* lnb  = (const float*)d_in[21];
  const float* Wout = (const float*)d_in[22];
  const float* bout = (const float*)d_in[23];

  const int* src = ei;
  const int* dst = ei + NE;

  float* ws = (float*)d_ws;
  float* h  = ws + 0 * (NN * C);
  float* t0 = ws + 1 * (NN * C);   // xw, then oproj output
  float* t1 = ws + 2 * (NN * C);
  float* t2 = ws + 3 * (NN * C);
  float* t3 = ws + 4 * (NN * C);
  float* t4 = ws + 5 * (NN * C);
  u16* Qb  = (u16*)(ws + 6 * (NN * C));
  u16* Kb  = Qb + NN * C;
  u16* Vtb = Kb + NN * C;
  float* dinv = (float*)(Vtb + NN * C);
  float* statsAll = dinv + NN;        // 12 x 128
  int* degi   = (int*)(statsAll + 1536);
  int* rowptr = degi + NN;            // NN+1
  int* cursor = rowptr + NN + 8;
  int* esrc   = cursor + NN;          // NE

  dim3 B(256);

  // ---- setup: CSR + dinv (recomputed every call; deterministic inputs)
  zero_setup<<<32, B, 0, stream>>>(statsAll, degi);
  deg_kernel<<<NE / 256, B, 0, stream>>>(dst, degi);
  prefix_kernel<<<1, B, 0, stream>>>(degi, rowptr, cursor);
  dinv_kernel<<<NN / 256, B, 0, stream>>>(degi, dinv);
  fill_kernel<<<NE / 256, B, 0, stream>>>(src, dst, cursor, esrc);

  gemm_in_kernel<<<NN * C / 256, B, 0, stream>>>(x, W_in, b_in, h);

  for (int l = 0; l < NL; ++l) {
    float* s1 = statsAll + l * 384;
    float* s2 = s1 + 128;
    float* s3 = s1 + 256;

    // ---- local GCN branch + residual -> t1, stats1
    gcn_gemm_init<<<NN * C / 256, B, 0, stream>>>(h, gcnW + l * C * C, gcnB + l * C, dinv, t0, t1);
    gcn_gather<<<NN / 4, B, 0, stream>>>(rowptr, esrc, t0, dinv, t1);
    bn_stats<<<256, B, 0, stream>>>(t1, s1);

    // ---- global attention branch + residual -> t0, stats2
    qkv_kernel<<<NN * 192 / 256, B, 0, stream>>>(h, Wqkv + l * 192 * C, bqkv + l * 192, Qb, Kb, Vtb);
    attn_mfma<<<256, 512, 0, stream>>>(Qb, Kb, Vtb, t2);
    oproj_kernel<<<NN * C / 256, B, 0, stream>>>(t2, Wo + l * C * C, bo + l * C, h, t0);
    bn_stats<<<256, B, 0, stream>>>(t0, s2);

    // ---- combine + MLP + BN3 + LN + ReLU -> h
    combine_kernel<<<NN * C / 256, B, 0, stream>>>(t1, t0, s1, s2, bn1g + l * C, bn1b + l * C,
                                                   bn2g + l * C, bn2b + l * C, t3);
    mlp_kernel<<<NN / 32, B, 0, stream>>>(t3, W1 + l * C * 2 * C, b1 + l * 2 * C,
                                          W2 + l * 2 * C * C, b2 + l * C, t4);
    bn_stats<<<256, B, 0, stream>>>(t4, s3);
    bn3_ln_relu<<<NN / 4, B, 0, stream>>>(t4, s3, bn3g + l * C, bn3b + l * C,
                                          lng + l * C, lnb + l * C, h);
  }

  final_kernel<<<NN / 4, B, 0, stream>>>(h, Wout, bout, (float*)d_out);
}

// Round 4
// 909.795 us; speedup vs baseline: 4.3517x; 1.0467x over previous
//
#include <hip/hip_runtime.h>
#include <math.h>

#define NN 8192
#define NE 131072
#define CIN 128
#define C 64
#define NL 4
#define COUT 21
#define EPSV 1e-5f

typedef unsigned short u16;
typedef __attribute__((ext_vector_type(8))) short short8;
typedef __attribute__((ext_vector_type(4))) float f32x4;
typedef __attribute__((ext_vector_type(4))) unsigned int u32x4;

__device__ __forceinline__ u16 f2bf(float x) {
  unsigned int u = __float_as_uint(x);
  u += 0x7FFF + ((u >> 16) & 1);
  return (u16)(u >> 16);
}

__device__ __forceinline__ unsigned cvtpk(float a, float b) {
  unsigned r;
  asm("v_cvt_pk_bf16_f32 %0, %1, %2" : "=v"(r) : "v"(a), "v"(b));
  return r;
}

// ---------------------------------------------------------------- setup
__global__ void zero_setup(float* __restrict__ stats, int* __restrict__ degi) {
  int i = blockIdx.x * 256 + threadIdx.x;
  if (i < 1536) stats[i] = 0.f;
  if (i < NN) degi[i] = 0;
}

__global__ void deg_kernel(const int* __restrict__ dst, int* __restrict__ degi) {
  int e = blockIdx.x * 256 + threadIdx.x;
  if (e < NE) atomicAdd(&degi[dst[e]], 1);
}

__global__ __launch_bounds__(256) void prefix_kernel(const int* __restrict__ degi,
                                                     int* __restrict__ rowptr,
                                                     int* __restrict__ cursor) {
  __shared__ int part[256];
  int t = threadIdx.x;
  int base = t * 32;
  int loc[32];
  int s = 0;
#pragma unroll
  for (int i = 0; i < 32; ++i) { loc[i] = s; s += degi[base + i]; }
  part[t] = s;
  __syncthreads();
  for (int off = 1; off < 256; off <<= 1) {
    int v = (t >= off) ? part[t - off] : 0;
    __syncthreads();
    part[t] += v;
    __syncthreads();
  }
  int chunkbase = (t == 0) ? 0 : part[t - 1];
#pragma unroll
  for (int i = 0; i < 32; ++i) {
    int v = chunkbase + loc[i];
    rowptr[base + i] = v;
    cursor[base + i] = v;
  }
  if (t == 255) rowptr[NN] = part[255];
}

__global__ void dinv_kernel(const int* __restrict__ degi, float* __restrict__ dinv) {
  int i = blockIdx.x * 256 + threadIdx.x;
  if (i < NN) dinv[i] = rsqrtf((float)degi[i] + 1.0f);
}

__global__ void fill_kernel(const int* __restrict__ src, const int* __restrict__ dst,
                            int* __restrict__ cursor, int* __restrict__ esrc) {
  int e = blockIdx.x * 256 + threadIdx.x;
  if (e < NE) {
    int d = dst[e];
    int pos = atomicAdd(&cursor[d], 1);
    esrc[pos] = src[e];
  }
}

// ------------------------------------------------------------- input GEMM
__global__ __launch_bounds__(256) void gemm_in_kernel(const float* __restrict__ X,
                                                      const float* __restrict__ W,
                                                      const float* __restrict__ b,
                                                      float* __restrict__ Y) {
  int idx = blockIdx.x * 256 + threadIdx.x;
  int n = idx >> 6, c = idx & 63;
  const float* xr = X + n * CIN;
  float acc = b[c];
#pragma unroll 16
  for (int k = 0; k < CIN; ++k) acc = fmaf(xr[k], W[k * C + c], acc);
  Y[idx] = acc;
}

// --------------------------------------------- GCN gemm + self-loop init (fused)
__global__ __launch_bounds__(256) void gcn_gemm_init(const float* __restrict__ H,
                                                     const float* __restrict__ Wg,
                                                     const float* __restrict__ gb,
                                                     const float* __restrict__ dinv,
                                                     float* __restrict__ xw,
                                                     float* __restrict__ t1) {
  int idx = blockIdx.x * 256 + threadIdx.x;
  int n = idx >> 6, c = idx & 63;
  const float* xr = H + n * 64;
  float acc = 0.f;
#pragma unroll 16
  for (int k = 0; k < 64; ++k) acc = fmaf(xr[k], Wg[k * 64 + c], acc);
  xw[idx] = acc;
  float di = dinv[n];
  t1[idx] = acc * di * di + gb[c] + H[idx];
}

// --------------------------------------------- GCN gather (CSR, no atomics)
__global__ __launch_bounds__(256) void gcn_gather(const int* __restrict__ rowptr,
                                                  const int* __restrict__ esrc,
                                                  const float* __restrict__ xw,
                                                  const float* __restrict__ dinv,
                                                  float* __restrict__ t1) {
  int w = threadIdx.x >> 6, lane = threadIdx.x & 63;
  int d = blockIdx.x * 4 + w;
  int beg = rowptr[d], end = rowptr[d + 1];
  float acc = 0.f;
  for (int i = beg; i < end; ++i) {
    int s = esrc[i];
    acc = fmaf(xw[s * 64 + lane], dinv[s], acc);
  }
  int idx = d * 64 + lane;
  t1[idx] = t1[idx] + acc * dinv[d];
}

// ---------------------------------------------------------------- BN stats
__global__ __launch_bounds__(256) void bn_stats(const float* __restrict__ A,
                                                float* __restrict__ stats) {
  int t = threadIdx.x;
  int c = t & 63, rr = t >> 6;
  int r0 = blockIdx.x * 32;
  float s = 0.f, ss = 0.f;
  for (int i = rr; i < 32; i += 4) {
    float x = A[(r0 + i) * 64 + c];
    s += x; ss += x * x;
  }
  __shared__ float sb[4][64], ssb[4][64];
  sb[rr][c] = s; ssb[rr][c] = ss;
  __syncthreads();
  if (t < 64) {
    atomicAdd(&stats[t], sb[0][t] + sb[1][t] + sb[2][t] + sb[3][t]);
    atomicAdd(&stats[64 + t], ssb[0][t] + ssb[1][t] + ssb[2][t] + ssb[3][t]);
  }
}

// --------------------------------------------------------- QKV projection
// Q,K bf16 d-permuted; V plain f32 [N][64] (coalesced; transposed separately)
__global__ __launch_bounds__(256) void qkv_kernel(const float* __restrict__ H,
                                                  const float* __restrict__ Wq,
                                                  const float* __restrict__ bq,
                                                  u16* __restrict__ Qb,
                                                  u16* __restrict__ Kb,
                                                  float* __restrict__ Vf) {
  int idx = blockIdx.x * 256 + threadIdx.x;   // N*192
  int n = idx / 192, j = idx % 192;
  const float* xr = H + n * C;
  float acc = bq[j];
#pragma unroll 16
  for (int c = 0; c < C; ++c) acc = fmaf(xr[c], Wq[j * C + c], acc);
  int jj = j & 63;
  int pc = (jj & ~31) | (jj & 3) | (((jj >> 2) & 3) << 3) | (((jj >> 4) & 1) << 2);
  if (j < 64) {
    Qb[n * 64 + pc] = f2bf(acc * 0.18033688011112043f);  // 0.125 * log2(e)
  } else if (j < 128) {
    Kb[n * 64 + pc] = f2bf(acc);
  } else {
    Vf[n * 64 + jj] = acc;
  }
}

// --------------------------------------------------- V transpose -> bf16 [64][NN]
// Vt[jj][perm(n)] = Vf[n][jj]; perm applies within 32-key groups.
__global__ __launch_bounds__(256) void vtrans_kernel(const float* __restrict__ Vf,
                                                     u16* __restrict__ Vt) {
  __shared__ float lds[64][65];
  int t = threadIdx.x;
  int n0 = blockIdx.x * 64;
#pragma unroll
  for (int i = 0; i < 16; ++i) {
    int e = i * 256 + t;
    lds[e >> 6][e & 63] = Vf[(n0 + (e >> 6)) * 64 + (e & 63)];
  }
  __syncthreads();
  int jj = t >> 2, blk = t & 3;
  unsigned wv[8];
#pragma unroll
  for (int u = 0; u < 8; ++u) {
    int pn0 = blk * 16 + u * 2, pn1 = pn0 + 1;
    int nl0 = (pn0 & 32) | (((pn0 >> 2) & 1) << 4) | (((pn0 >> 3) & 3) << 2) | (pn0 & 3);
    int nl1 = (pn1 & 32) | (((pn1 >> 2) & 1) << 4) | (((pn1 >> 3) & 3) << 2) | (pn1 & 3);
    wv[u] = cvtpk(lds[nl0][jj], lds[nl1][jj]);
  }
  u16* dp = Vt + (size_t)jj * NN + n0 + blk * 16;
  *(u32x4*)dp = u32x4{wv[0], wv[1], wv[2], wv[3]};
  *(u32x4*)(dp + 8) = u32x4{wv[4], wv[5], wv[6], wv[7]};
}

// ------------------------------------------------------------ MFMA flash attention
// grid 256 = 128 Q-tiles x 2 key-splits; 512 threads (8 waves). Block: 64 Q rows,
// 4096 keys; wave w: keys [ks*4096 + w*512, +512) = 8 tiles of 64. K register
// double-buffered (distance-1 prefetch), V issued at compute start (latency hidden
// under QK+softmax). Fixed-max log2-domain softmax. Partial O (64x64) + l -> ws.
__device__ __forceinline__ void loadK(short8 (&kf)[8], const u16* kb, int koff) {
#pragma unroll
  for (int jt = 0; jt < 4; ++jt)
#pragma unroll
    for (int s = 0; s < 2; ++s)
      kf[jt * 2 + s] = *(const short8*)(kb + koff + jt * 1024 + s * 32);
}

__device__ __forceinline__ void loadV(short8 (&vf)[8], const u16* vb, int voff) {
#pragma unroll
  for (int dt = 0; dt < 4; ++dt)
#pragma unroll
    for (int s = 0; s < 2; ++s)
      vf[dt * 2 + s] = *(const short8*)(vb + voff + dt * 16 * NN + s * 32);
}

__device__ __forceinline__ void computeTile(const short8 (&kf)[8], const short8 (&vf)[8],
                                            const short8 (&qf)[4][2],
                                            f32x4 (&o)[4][4], float (&ll)[4]) {
#pragma unroll
  for (int pair = 0; pair < 2; ++pair) {
    f32x4 st[2][4] = {};
#pragma unroll
    for (int s = 0; s < 2; ++s)
#pragma unroll
      for (int jp = 0; jp < 2; ++jp) {
        short8 kfrag = kf[(pair * 2 + jp) * 2 + s];
#pragma unroll
        for (int it = 0; it < 4; ++it)
          st[jp][it] = __builtin_amdgcn_mfma_f32_16x16x32_bf16(kfrag, qf[it][s], st[jp][it], 0, 0, 0);
      }
    short8 pf[4];
#pragma unroll
    for (int it = 0; it < 4; ++it) {
      float p[8];
#pragma unroll
      for (int jp = 0; jp < 2; ++jp)
#pragma unroll
        for (int r = 0; r < 4; ++r) p[jp * 4 + r] = exp2f(st[jp][it][r]);
      float ps = ((p[0] + p[1]) + (p[2] + p[3])) + ((p[4] + p[5]) + (p[6] + p[7]));
      ps += __shfl_xor(ps, 16);
      ps += __shfl_xor(ps, 32);
      ll[it] += ps;
      u32x4 a;
      a[0] = cvtpk(p[0], p[1]); a[1] = cvtpk(p[2], p[3]);
      a[2] = cvtpk(p[4], p[5]); a[3] = cvtpk(p[6], p[7]);
      pf[it] = __builtin_bit_cast(short8, a);
    }
#pragma unroll
    for (int dt = 0; dt < 4; ++dt) {
      short8 vfrag = vf[dt * 2 + pair];
#pragma unroll
      for (int it = 0; it < 4; ++it)
        o[dt][it] = __builtin_amdgcn_mfma_f32_16x16x32_bf16(vfrag, pf[it], o[dt][it], 0, 0, 0);
    }
  }
}

__global__ __launch_bounds__(512, 2)
void attn_mfma(const u16* __restrict__ Qb, const u16* __restrict__ Kb,
               const u16* __restrict__ Vtb, float* __restrict__ Opart,
               float* __restrict__ Lpart) {
  __shared__ float fsm[2 * 64 * 68 + 2 * 64];
  const int tid = threadIdx.x;
  const int lane = tid & 63;
  const int w = tid >> 6;
  const int qt = blockIdx.x >> 1, ks = blockIdx.x & 1;
  const int qbase = qt * 64;
  const int kv0 = ks * 4096 + w * 512;
  const int r = lane & 15, q = lane >> 4;

  short8 qf[4][2];
#pragma unroll
  for (int it = 0; it < 4; ++it)
#pragma unroll
    for (int s = 0; s < 2; ++s)
      qf[it][s] = *(const short8*)(Qb + (size_t)(qbase + it * 16 + r) * 64 + s * 32 + q * 8);

  f32x4 o[4][4] = {};
  float ll[4] = {0.f, 0.f, 0.f, 0.f};

  const u16* kb = Kb + (size_t)(kv0 + r) * 64 + q * 8;
  const u16* vb = Vtb + (size_t)r * NN + kv0 + q * 8;

  short8 kA[8], kB[8], vf[8];
  loadK(kA, kb, 0);
#pragma unroll 1
  for (int t = 0; t < 8; t += 2) {
    loadV(vf, vb, t * 64);
    loadK(kB, kb, (t + 1) * 4096);
    computeTile(kA, vf, qf, o, ll);
    loadV(vf, vb, (t + 1) * 64);
    if (t + 2 < 8) loadK(kA, kb, (t + 2) * 4096);
    computeTile(kB, vf, qf, o, ll);
  }

  // ---- 8-wave merge: 2 LDS bufs, 4 rounds
  float* buf = fsm + (w & 1) * (64 * 68);
  float* lb = fsm + 2 * 64 * 68 + (w & 1) * 64;
  for (int rr = 0; rr < 4; ++rr) {
    if ((w >> 1) == rr) {
      if (rr == 0) {
#pragma unroll
        for (int dt = 0; dt < 4; ++dt)
#pragma unroll
          for (int it = 0; it < 4; ++it)
            *(f32x4*)&buf[(it * 16 + r) * 68 + dt * 16 + q * 4] = o[dt][it];
        if (lane < 16)
#pragma unroll
          for (int it = 0; it < 4; ++it) lb[it * 16 + lane] = ll[it];
      } else {
#pragma unroll
        for (int dt = 0; dt < 4; ++dt)
#pragma unroll
          for (int it = 0; it < 4; ++it) {
            float* p = &buf[(it * 16 + r) * 68 + dt * 16 + q * 4];
            *(f32x4*)p = *(const f32x4*)p + o[dt][it];
          }
        if (lane < 16)
#pragma unroll
          for (int it = 0; it < 4; ++it) lb[it * 16 + lane] += ll[it];
      }
    }
    __syncthreads();
  }

  int row = tid >> 3, d0 = (tid & 7) * 8;
  float* outp = Opart + (size_t)(qt * 2 + ks) * 4096 + row * 64 + d0;
  const float* b0 = fsm + row * 68 + d0;
  const float* b1 = b0 + 64 * 68;
#pragma unroll
  for (int j = 0; j < 8; ++j) outp[j] = b0[j] + b1[j];
  if (tid < 64) Lpart[(qt * 2 + ks) * 64 + tid] = fsm[2 * 64 * 68 + tid] + fsm[2 * 64 * 68 + 64 + tid];
}

// ------------------------------------- O-projection (+2-way merge +res +bias)
__global__ __launch_bounds__(256) void oproj_kernel(const float* __restrict__ Opart,
                                                    const float* __restrict__ Lpart,
                                                    const float* __restrict__ W,
                                                    const float* __restrict__ bias,
                                                    const float* __restrict__ res,
                                                    float* __restrict__ Y) {
  int idx = blockIdx.x * 256 + threadIdx.x;
  int n = idx >> 6, m = idx & 63;
  int qt = n >> 6, row = n & 63;
  const float* O0 = Opart + (size_t)qt * 8192 + row * 64;
  const float* O1 = O0 + 4096;
  float inv = 1.f / (Lpart[qt * 128 + row] + Lpart[qt * 128 + 64 + row]);
  float acc = 0.f;
#pragma unroll 16
  for (int k = 0; k < 64; ++k) acc = fmaf(O0[k] + O1[k], W[m * 64 + k], acc);
  Y[idx] = acc * inv + bias[m] + res[idx];
}

// ----------------------------- fused combine(bn1+bn2) + MLP (+relu +residual)
__global__ __launch_bounds__(256) void mlp_kernel(const float* __restrict__ t1,
                                                  const float* __restrict__ t0,
                                                  const float* __restrict__ s1,
                                                  const float* __restrict__ s2,
                                                  const float* __restrict__ g1,
                                                  const float* __restrict__ bb1,
                                                  const float* __restrict__ g2,
                                                  const float* __restrict__ bb2,
                                                  const float* __restrict__ W1,
                                                  const float* __restrict__ b1,
                                                  const float* __restrict__ W2,
                                                  const float* __restrict__ b2,
                                                  float* __restrict__ t4) {
  __shared__ float rows[32][68];
  __shared__ float mid[32][132];
  int t = threadIdx.x;
  int r0 = blockIdx.x * 32;
  for (int i = t; i < 2048; i += 256) {
    int rr = i >> 6, c = i & 63;
    int idx = (r0 + rr) * 64 + c;
    float m1 = s1[c] * (1.f / NN);
    float v1 = s1[64 + c] * (1.f / NN) - m1 * m1;
    float m2 = s2[c] * (1.f / NN);
    float v2 = s2[64 + c] * (1.f / NN) - m2 * m2;
    rows[rr][c] = (t1[idx] - m1) * rsqrtf(v1 + EPSV) * g1[c] + bb1[c] +
                  (t0[idx] - m2) * rsqrtf(v2 + EPSV) * g2[c] + bb2[c];
  }
  __syncthreads();
  int r = t >> 3;
  {
    int m0 = (t & 7) * 16;
    float acc[16];
#pragma unroll
    for (int j = 0; j < 16; ++j) acc[j] = b1[m0 + j];
    for (int k = 0; k < 64; ++k) {
      float xv = rows[r][k];
#pragma unroll
      for (int j = 0; j < 16; ++j) acc[j] = fmaf(xv, W1[k * 128 + m0 + j], acc[j]);
    }
#pragma unroll
    for (int j = 0; j < 16; ++j) mid[r][m0 + j] = fmaxf(acc[j], 0.f);
  }
  __syncthreads();
  {
    int c0 = (t & 7) * 8;
    float oc[8];
#pragma unroll
    for (int j = 0; j < 8; ++j) oc[j] = b2[c0 + j] + rows[r][c0 + j];
    for (int k = 0; k < 128; ++k) {
      float mv = mid[r][k];
#pragma unroll
      for (int j = 0; j < 8; ++j) oc[j] = fmaf(mv, W2[k * 64 + c0 + j], oc[j]);
    }
#pragma unroll
    for (int j = 0; j < 8; ++j) t4[(r0 + r) * 64 + c0 + j] = oc[j];
  }
}

// ------------------------------------------- BN3 + LayerNorm + ReLU (fused)
__global__ __launch_bounds__(256) void bn3_ln_relu(const float* __restrict__ t4,
                                                   const float* __restrict__ s3,
                                                   const float* __restrict__ g3,
                                                   const float* __restrict__ b3,
                                                   const float* __restrict__ lg,
                                                   const float* __restrict__ lb,
                                                   float* __restrict__ H) {
  int wv = threadIdx.x >> 6, lane = threadIdx.x & 63;
  int n = blockIdx.x * 4 + wv;
  float m3 = s3[lane] * (1.f / NN);
  float v3 = s3[64 + lane] * (1.f / NN) - m3 * m3;
  float x = (t4[n * 64 + lane] - m3) * rsqrtf(v3 + EPSV) * g3[lane] + b3[lane];
  float s = x, ss = x * x;
  for (int o = 32; o > 0; o >>= 1) {
    s += __shfl_xor(s, o, 64);
    ss += __shfl_xor(ss, o, 64);
  }
  float m = s * (1.f / 64), v = ss * (1.f / 64) - m * m;
  float y = (x - m) * rsqrtf(v + EPSV) * lg[lane] + lb[lane];
  H[n * 64 + lane] = fmaxf(y, 0.f);
}

// ------------------------------------------- final GEMM (64x21) + log_softmax
__global__ __launch_bounds__(256) void final_kernel(const float* __restrict__ H,
                                                    const float* __restrict__ Wout,
                                                    const float* __restrict__ bout,
                                                    float* __restrict__ out) {
  int w = threadIdx.x >> 6, lane = threadIdx.x & 63;
  int n = blockIdx.x * 4 + w;
  const float* hr = H + n * 64;
  float acc = (lane < COUT) ? bout[lane] : -INFINITY;
  if (lane < COUT) {
#pragma unroll 16
    for (int k = 0; k < 64; ++k) acc = fmaf(hr[k], Wout[k * COUT + lane], acc);
  }
  float mx = acc;
  for (int o = 32; o > 0; o >>= 1) mx = fmaxf(mx, __shfl_xor(mx, o, 64));
  float e = __expf(acc - mx);
  float se = e;
  for (int o = 32; o > 0; o >>= 1) se += __shfl_xor(se, o, 64);
  float lse = mx + logf(se);
  if (lane < COUT) out[n * COUT + lane] = acc - lse;
}

// ================================================================ launch
extern "C" void kernel_launch(void* const* d_in, const int* in_sizes, int n_in,
                              void* d_out, int out_size, void* d_ws, size_t ws_size,
                              hipStream_t stream) {
  const float* x    = (const float*)d_in[0];
  const int*   ei   = (const int*)d_in[1];
  const float* W_in = (const float*)d_in[2];
  const float* b_in = (const float*)d_in[3];
  const float* gcnW = (const float*)d_in[4];
  const float* gcnB = (const float*)d_in[5];
  const float* Wqkv = (const float*)d_in[6];
  const float* bqkv = (const float*)d_in[7];
  const float* Wo   = (const float*)d_in[8];
  const float* bo   = (const float*)d_in[9];
  const float* bn1g = (const float*)d_in[10];
  const float* bn1b = (const float*)d_in[11];
  const float* bn2g = (const float*)d_in[12];
  const float* bn2b = (const float*)d_in[13];
  const float* bn3g = (const float*)d_in[14];
  const float* bn3b = (const float*)d_in[15];
  const float* W1   = (const float*)d_in[16];
  const float* b1   = (const float*)d_in[17];
  const float* W2   = (const float*)d_in[18];
  const float* b2   = (const float*)d_in[19];
  const float* lng  = (const float*)d_in[20];
  const float* lnb  = (const float*)d_in[21];
  const float* Wout = (const float*)d_in[22];
  const float* bout = (const float*)d_in[23];

  const int* src = ei;
  const int* dst = ei + NE;

  float* ws = (float*)d_ws;
  float* h     = ws + 0 * (NN * C);
  float* t0    = ws + 1 * (NN * C);   // xw, then oproj output
  float* t1    = ws + 2 * (NN * C);
  float* Opart = ws + 3 * (NN * C);   // spans t2+t3 (4MB: 128qt x 2ks x 64 x 64)
  float* t4    = ws + 5 * (NN * C);   // Vf32, then mlp output
  u16* Qb  = (u16*)(ws + 6 * (NN * C));
  u16* Kb  = Qb + NN * C;
  u16* Vtb = Kb + NN * C;
  float* dinv = (float*)(Vtb + NN * C);
  float* statsAll = dinv + NN;        // 12 x 128
  float* Lpart = statsAll + 1536;     // 128 x 2 x 64
  int* degi   = (int*)(Lpart + 16384);
  int* rowptr = degi + NN;            // NN+1
  int* cursor = rowptr + NN + 8;
  int* esrc   = cursor + NN;          // NE

  dim3 B(256);

  // ---- setup: CSR + dinv (recomputed every call; deterministic inputs)
  zero_setup<<<32, B, 0, stream>>>(statsAll, degi);
  deg_kernel<<<NE / 256, B, 0, stream>>>(dst, degi);
  prefix_kernel<<<1, B, 0, stream>>>(degi, rowptr, cursor);
  dinv_kernel<<<NN / 256, B, 0, stream>>>(degi, dinv);
  fill_kernel<<<NE / 256, B, 0, stream>>>(src, dst, cursor, esrc);

  gemm_in_kernel<<<NN * C / 256, B, 0, stream>>>(x, W_in, b_in, h);

  for (int l = 0; l < NL; ++l) {
    float* s1 = statsAll + l * 384;
    float* s2 = s1 + 128;
    float* s3 = s1 + 256;

    // ---- local GCN branch + residual -> t1, stats1
    gcn_gemm_init<<<NN * C / 256, B, 0, stream>>>(h, gcnW + l * C * C, gcnB + l * C, dinv, t0, t1);
    gcn_gather<<<NN / 4, B, 0, stream>>>(rowptr, esrc, t0, dinv, t1);
    bn_stats<<<256, B, 0, stream>>>(t1, s1);

    // ---- global attention branch + residual -> t0, stats2
    qkv_kernel<<<NN * 192 / 256, B, 0, stream>>>(h, Wqkv + l * 192 * C, bqkv + l * 192, Qb, Kb, t4);
    vtrans_kernel<<<NN / 64, B, 0, stream>>>(t4, Vtb);
    attn_mfma<<<256, 512, 0, stream>>>(Qb, Kb, Vtb, Opart, Lpart);
    oproj_kernel<<<NN * C / 256, B, 0, stream>>>(Opart, Lpart, Wo + l * C * C, bo + l * C, h, t0);
    bn_stats<<<256, B, 0, stream>>>(t0, s2);

    // ---- combine + MLP -> t4, BN3 + LN + ReLU -> h
    mlp_kernel<<<NN / 32, B, 0, stream>>>(t1, t0, s1, s2, bn1g + l * C, bn1b + l * C,
                                          bn2g + l * C, bn2b + l * C,
                                          W1 + l * C * 2 * C, b1 + l * 2 * C,
                                          W2 + l * 2 * C * C, b2 + l * C, t4);
    bn_stats<<<256, B, 0, stream>>>(t4, s3);
    bn3_ln_relu<<<NN / 4, B, 0, stream>>>(t4, s3, bn3g + l * C, bn3b + l * C,
                                          lng + l * C, lnb + l * C, h);
  }

  final_kernel<<<NN / 4, B, 0, stream>>>(h, Wout, bout, (float*)d_out);
}

// Round 5
// 632.275 us; speedup vs baseline: 6.2618x; 1.4389x over previous
//
#include <hip/hip_runtime.h>
#include <math.h>

#define NN 8192
#define NE 131072
#define CIN 128
#define C 64
#define NL 4
#define COUT 21
#define EPSV 1e-5f
#define ALPHA 0.18033688011112043f  // 0.125 * log2(e)

typedef unsigned short u16;
typedef __attribute__((ext_vector_type(8))) short short8;
typedef __attribute__((ext_vector_type(4))) float f32x4;
typedef __attribute__((ext_vector_type(4))) unsigned int u32x4;
typedef __attribute__((ext_vector_type(2))) unsigned int u32x2;

__device__ __forceinline__ u16 f2bf(float x) {
  unsigned int u = __float_as_uint(x);
  u += 0x7FFF + ((u >> 16) & 1);
  return (u16)(u >> 16);
}

__device__ __forceinline__ unsigned cvtpk(float a, float b) {
  unsigned r;
  asm("v_cvt_pk_bf16_f32 %0, %1, %2" : "=v"(r) : "v"(a), "v"(b));
  return r;
}

__device__ __forceinline__ int pcmap(int c) {  // k-dim permutation (within 32)
  return (c & 32) | (c & 3) | (((c >> 2) & 3) << 3) | (((c >> 4) & 1) << 2);
}

// ---------------------------------------------------------------- setup
__global__ void zero_setup(float* __restrict__ stats, int* __restrict__ degi) {
  int i = blockIdx.x * 256 + threadIdx.x;
  if (i < 1536) stats[i] = 0.f;
  if (i < NN) degi[i] = 0;
}

__global__ void deg_kernel(const int* __restrict__ dst, int* __restrict__ degi) {
  int e = blockIdx.x * 256 + threadIdx.x;
  if (e < NE) atomicAdd(&degi[dst[e]], 1);
}

__global__ __launch_bounds__(256) void prefix_kernel(const int* __restrict__ degi,
                                                     int* __restrict__ rowptr,
                                                     int* __restrict__ cursor) {
  __shared__ int part[256];
  int t = threadIdx.x;
  int base = t * 32;
  int loc[32];
  int s = 0;
#pragma unroll
  for (int i = 0; i < 32; ++i) { loc[i] = s; s += degi[base + i]; }
  part[t] = s;
  __syncthreads();
  for (int off = 1; off < 256; off <<= 1) {
    int v = (t >= off) ? part[t - off] : 0;
    __syncthreads();
    part[t] += v;
    __syncthreads();
  }
  int chunkbase = (t == 0) ? 0 : part[t - 1];
#pragma unroll
  for (int i = 0; i < 32; ++i) {
    int v = chunkbase + loc[i];
    rowptr[base + i] = v;
    cursor[base + i] = v;
  }
  if (t == 255) rowptr[NN] = part[255];
}

__global__ void dinv_kernel(const int* __restrict__ degi, float* __restrict__ dinv) {
  int i = blockIdx.x * 256 + threadIdx.x;
  if (i < NN) dinv[i] = rsqrtf((float)degi[i] + 1.0f);
}

__global__ void fill_kernel(const int* __restrict__ src, const int* __restrict__ dst,
                            int* __restrict__ cursor, int* __restrict__ esrc) {
  int e = blockIdx.x * 256 + threadIdx.x;
  if (e < NE) {
    int d = dst[e];
    int pos = atomicAdd(&cursor[d], 1);
    esrc[pos] = src[e];
  }
}

// ------------------------------------- weight prep: bf16 + pc-permute k-dim
__global__ void prep_weights(const float* __restrict__ Wqkv, const float* __restrict__ Wo,
                             u16* __restrict__ Wqp, u16* __restrict__ Wop) {
  int idx = blockIdx.x * 256 + threadIdx.x;   // 65536
  if (idx < NL * 192 * 64) {
    int l = idx / 12288, rem = idx % 12288;
    int j = rem >> 6, c = rem & 63;
    Wqp[l * 12288 + j * 64 + pcmap(c)] = f2bf(Wqkv[idx]);
  } else {
    int i2 = idx - NL * 192 * 64;             // 16384
    int l = i2 >> 12, m = (i2 >> 6) & 63, k = i2 & 63;
    Wop[l * 4096 + m * 64 + pcmap(k)] = f2bf(Wo[i2]);
  }
}

// ------------------------------------------------------------- input GEMM
__global__ __launch_bounds__(256) void gemm_in_kernel(const float* __restrict__ X,
                                                      const float* __restrict__ W,
                                                      const float* __restrict__ b,
                                                      float* __restrict__ Y,
                                                      u16* __restrict__ hb) {
  int idx = blockIdx.x * 256 + threadIdx.x;
  int n = idx >> 6, c = idx & 63;
  const float* xr = X + n * CIN;
  float acc = b[c];
#pragma unroll 16
  for (int k = 0; k < CIN; ++k) acc = fmaf(xr[k], W[k * C + c], acc);
  Y[idx] = acc;
  hb[n * 64 + pcmap(c)] = f2bf(acc);
}

// --------------------------------------------- GCN gemm + self-loop init (fused)
__global__ __launch_bounds__(256) void gcn_gemm_init(const float* __restrict__ H,
                                                     const float* __restrict__ Wg,
                                                     const float* __restrict__ gb,
                                                     const float* __restrict__ dinv,
                                                     float* __restrict__ xw,
                                                     float* __restrict__ t1) {
  int idx = blockIdx.x * 256 + threadIdx.x;
  int n = idx >> 6, c = idx & 63;
  const float* xr = H + n * 64;
  float acc = 0.f;
#pragma unroll 16
  for (int k = 0; k < 64; ++k) acc = fmaf(xr[k], Wg[k * 64 + c], acc);
  xw[idx] = acc;
  float di = dinv[n];
  t1[idx] = acc * di * di + gb[c] + H[idx];
}

// --------------------------------------------- GCN gather (CSR, no atomics)
__global__ __launch_bounds__(256) void gcn_gather(const int* __restrict__ rowptr,
                                                  const int* __restrict__ esrc,
                                                  const float* __restrict__ xw,
                                                  const float* __restrict__ dinv,
                                                  float* __restrict__ t1) {
  int w = threadIdx.x >> 6, lane = threadIdx.x & 63;
  int d = blockIdx.x * 4 + w;
  int beg = rowptr[d], end = rowptr[d + 1];
  float acc = 0.f;
  for (int i = beg; i < end; ++i) {
    int s = esrc[i];
    acc = fmaf(xw[s * 64 + lane], dinv[s], acc);
  }
  int idx = d * 64 + lane;
  t1[idx] = t1[idx] + acc * dinv[d];
}

// ---------------------------------------------------------------- BN stats
__global__ __launch_bounds__(256) void bn_stats(const float* __restrict__ A,
                                                float* __restrict__ stats) {
  int t = threadIdx.x;
  int c = t & 63, rr = t >> 6;
  int r0 = blockIdx.x * 32;
  float s = 0.f, ss = 0.f;
  for (int i = rr; i < 32; i += 4) {
    float x = A[(r0 + i) * 64 + c];
    s += x; ss += x * x;
  }
  __shared__ float sb[4][64], ssb[4][64];
  sb[rr][c] = s; ssb[rr][c] = ss;
  __syncthreads();
  if (t < 64) {
    atomicAdd(&stats[t], sb[0][t] + sb[1][t] + sb[2][t] + sb[3][t]);
    atomicAdd(&stats[64 + t], ssb[0][t] + ssb[1][t] + ssb[2][t] + ssb[3][t]);
  }
}

// ------------------------------------------- QKV via MFMA (replaces qkv+vtrans)
// 256 blocks x 128 thr (2 waves). Block: rows [b*32, +32); wave w: rows +w*16.
// D: a_row=q*4+reg -> j, col=lane&15 -> n. Q/K stored pc-permuted (8B stores);
// V staged in LDS then transposed out with pn permutation.
__global__ __launch_bounds__(128) void qkv_mfma(const u16* __restrict__ hb,
                                                const u16* __restrict__ Wqp,
                                                const float* __restrict__ bq,
                                                u16* __restrict__ Qb,
                                                u16* __restrict__ Kb,
                                                u16* __restrict__ Vt) {
  __shared__ u16 ldsv[64 * 34];
  const int tid = threadIdx.x;
  const int lane = tid & 63, w = tid >> 6;
  const int r = lane & 15, q = lane >> 4;
  const int n0 = blockIdx.x * 32;
  const int n = n0 + w * 16 + r;

  short8 hf[2];
#pragma unroll
  for (int s = 0; s < 2; ++s)
    hf[s] = *(const short8*)(hb + (size_t)n * 64 + s * 32 + q * 8);

  f32x4 acc[12];
#pragma unroll
  for (int jt = 0; jt < 12; ++jt) {
    f32x4 a = {};
#pragma unroll
    for (int s = 0; s < 2; ++s) {
      short8 wf = *(const short8*)(Wqp + (jt * 16 + r) * 64 + s * 32 + q * 8);
      a = __builtin_amdgcn_mfma_f32_16x16x32_bf16(wf, hf[s], a, 0, 0, 0);
    }
    acc[jt] = a;
  }

#pragma unroll
  for (int jt = 0; jt < 12; ++jt) {
    f32x4 v = acc[jt] + *(const f32x4*)&bq[jt * 16 + q * 4];
    if (jt < 4) {
      v *= ALPHA;
      int pb = ((jt & 2) << 4) | (q << 3) | ((jt & 1) << 2);
      *(u32x2*)(Qb + (size_t)n * 64 + pb) = u32x2{cvtpk(v[0], v[1]), cvtpk(v[2], v[3])};
    } else if (jt < 8) {
      int jk = jt - 4;
      int pb = ((jk & 2) << 4) | (q << 3) | ((jk & 1) << 2);
      *(u32x2*)(Kb + (size_t)n * 64 + pb) = u32x2{cvtpk(v[0], v[1]), cvtpk(v[2], v[3])};
    } else {
      int jj = (jt - 8) * 16 + q * 4;
      int nl = w * 16 + r;
#pragma unroll
      for (int e = 0; e < 4; ++e) ldsv[(jj + e) * 34 + nl] = f2bf(v[e]);
    }
  }
  __syncthreads();

  // transpose out: thread t -> d=t>>1, keys [half*16, +16) with pn permutation
  int jj = tid >> 1, half = tid & 1;
  unsigned wv[8];
#pragma unroll
  for (int u = 0; u < 8; ++u) {
    int p0 = half * 16 + u * 2, p1 = p0 + 1;
    int nl0 = (p0 & 3) | (((p0 >> 3) & 3) << 2) | (((p0 >> 2) & 1) << 4);
    int nl1 = (p1 & 3) | (((p1 >> 3) & 3) << 2) | (((p1 >> 2) & 1) << 4);
    wv[u] = ((unsigned)ldsv[jj * 34 + nl1] << 16) | ldsv[jj * 34 + nl0];
  }
  u16* dp = Vt + (size_t)jj * NN + n0 + half * 16;
  *(u32x4*)dp = u32x4{wv[0], wv[1], wv[2], wv[3]};
  *(u32x4*)(dp + 8) = u32x4{wv[4], wv[5], wv[6], wv[7]};
}

// ------------------------------------------------------------ MFMA flash attention
__device__ __forceinline__ void loadK(short8 (&kf)[8], const u16* kb, int koff) {
#pragma unroll
  for (int jt = 0; jt < 4; ++jt)
#pragma unroll
    for (int s = 0; s < 2; ++s)
      kf[jt * 2 + s] = *(const short8*)(kb + koff + jt * 1024 + s * 32);
}

__device__ __forceinline__ void loadV(short8 (&vf)[8], const u16* vb, int voff) {
#pragma unroll
  for (int dt = 0; dt < 4; ++dt)
#pragma unroll
    for (int s = 0; s < 2; ++s)
      vf[dt * 2 + s] = *(const short8*)(vb + voff + dt * 16 * NN + s * 32);
}

__device__ __forceinline__ void computeTile(const short8 (&kf)[8], const short8 (&vf)[8],
                                            const short8 (&qf)[4][2],
                                            f32x4 (&o)[4][4], float (&ll)[4]) {
#pragma unroll
  for (int pair = 0; pair < 2; ++pair) {
    f32x4 st[2][4] = {};
#pragma unroll
    for (int s = 0; s < 2; ++s)
#pragma unroll
      for (int jp = 0; jp < 2; ++jp) {
        short8 kfrag = kf[(pair * 2 + jp) * 2 + s];
#pragma unroll
        for (int it = 0; it < 4; ++it)
          st[jp][it] = __builtin_amdgcn_mfma_f32_16x16x32_bf16(kfrag, qf[it][s], st[jp][it], 0, 0, 0);
      }
    short8 pf[4];
#pragma unroll
    for (int it = 0; it < 4; ++it) {
      float p[8];
#pragma unroll
      for (int jp = 0; jp < 2; ++jp)
#pragma unroll
        for (int r = 0; r < 4; ++r) p[jp * 4 + r] = exp2f(st[jp][it][r]);
      float ps = ((p[0] + p[1]) + (p[2] + p[3])) + ((p[4] + p[5]) + (p[6] + p[7]));
      ps += __shfl_xor(ps, 16);
      ps += __shfl_xor(ps, 32);
      ll[it] += ps;
      u32x4 a;
      a[0] = cvtpk(p[0], p[1]); a[1] = cvtpk(p[2], p[3]);
      a[2] = cvtpk(p[4], p[5]); a[3] = cvtpk(p[6], p[7]);
      pf[it] = __builtin_bit_cast(short8, a);
    }
#pragma unroll
    for (int dt = 0; dt < 4; ++dt) {
      short8 vfrag = vf[dt * 2 + pair];
#pragma unroll
      for (int it = 0; it < 4; ++it)
        o[dt][it] = __builtin_amdgcn_mfma_f32_16x16x32_bf16(vfrag, pf[it], o[dt][it], 0, 0, 0);
    }
  }
}

__global__ __launch_bounds__(512, 2)
void attn_mfma(const u16* __restrict__ Qb, const u16* __restrict__ Kb,
               const u16* __restrict__ Vtb, float* __restrict__ Opart,
               float* __restrict__ Lpart) {
  __shared__ float fsm[2 * 64 * 68 + 2 * 64];
  const int tid = threadIdx.x;
  const int lane = tid & 63;
  const int w = tid >> 6;
  const int qt = blockIdx.x >> 1, ks = blockIdx.x & 1;
  const int qbase = qt * 64;
  const int kv0 = ks * 4096 + w * 512;
  const int r = lane & 15, q = lane >> 4;

  short8 qf[4][2];
#pragma unroll
  for (int it = 0; it < 4; ++it)
#pragma unroll
    for (int s = 0; s < 2; ++s)
      qf[it][s] = *(const short8*)(Qb + (size_t)(qbase + it * 16 + r) * 64 + s * 32 + q * 8);

  f32x4 o[4][4] = {};
  float ll[4] = {0.f, 0.f, 0.f, 0.f};

  const u16* kb = Kb + (size_t)(kv0 + r) * 64 + q * 8;
  const u16* vb = Vtb + (size_t)r * NN + kv0 + q * 8;

  short8 kA[8], kB[8], vf[8];
  loadK(kA, kb, 0);
#pragma unroll 1
  for (int t = 0; t < 8; t += 2) {
    loadV(vf, vb, t * 64);
    loadK(kB, kb, (t + 1) * 4096);
    computeTile(kA, vf, qf, o, ll);
    loadV(vf, vb, (t + 1) * 64);
    if (t + 2 < 8) loadK(kA, kb, (t + 2) * 4096);
    computeTile(kB, vf, qf, o, ll);
  }

  // ---- 8-wave merge: 2 LDS bufs, 4 rounds
  float* buf = fsm + (w & 1) * (64 * 68);
  float* lb = fsm + 2 * 64 * 68 + (w & 1) * 64;
  for (int rr = 0; rr < 4; ++rr) {
    if ((w >> 1) == rr) {
      if (rr == 0) {
#pragma unroll
        for (int dt = 0; dt < 4; ++dt)
#pragma unroll
          for (int it = 0; it < 4; ++it)
            *(f32x4*)&buf[(it * 16 + r) * 68 + dt * 16 + q * 4] = o[dt][it];
        if (lane < 16)
#pragma unroll
          for (int it = 0; it < 4; ++it) lb[it * 16 + lane] = ll[it];
      } else {
#pragma unroll
        for (int dt = 0; dt < 4; ++dt)
#pragma unroll
          for (int it = 0; it < 4; ++it) {
            float* p = &buf[(it * 16 + r) * 68 + dt * 16 + q * 4];
            *(f32x4*)p = *(const f32x4*)p + o[dt][it];
          }
        if (lane < 16)
#pragma unroll
          for (int it = 0; it < 4; ++it) lb[it * 16 + lane] += ll[it];
      }
    }
    __syncthreads();
  }

  int row = tid >> 3, d0 = (tid & 7) * 8;
  float* outp = Opart + (size_t)(qt * 2 + ks) * 4096 + row * 64 + d0;
  const float* b0 = fsm + row * 68 + d0;
  const float* b1 = b0 + 64 * 68;
#pragma unroll
  for (int j = 0; j < 8; ++j) outp[j] = b0[j] + b1[j];
  if (tid < 64) Lpart[(qt * 2 + ks) * 64 + tid] = fsm[2 * 64 * 68 + tid] + fsm[2 * 64 * 68 + 64 + tid];
}

// --------------------------- O-projection via MFMA (+merge +1/l +bias +res)
// 256 blocks x 256 thr; block = 32 rows. Phase A: merge halves, scale, bf16 ->
// LDS (pc-permuted, stride 72). Phase B: 4 waves x {ntile=w&1, 2 m-tiles}.
__global__ __launch_bounds__(256) void oproj_mfma(const float* __restrict__ Opart,
                                                  const float* __restrict__ Lpart,
                                                  const u16* __restrict__ Wop,
                                                  const float* __restrict__ bo,
                                                  const float* __restrict__ res,
                                                  float* __restrict__ Y) {
  __shared__ u16 ldso[32 * 72];
  const int tid = threadIdx.x;
  const int n0 = blockIdx.x * 32;
  const int qtile = n0 >> 6;

  {
    int row = tid >> 3, c0 = (tid & 7) * 8;
    int n = n0 + row, r64 = n & 63;
    float inv = 1.f / (Lpart[qtile * 128 + r64] + Lpart[qtile * 128 + 64 + r64]);
    const float* O0 = Opart + (size_t)(qtile * 2) * 4096 + ((n & 63) + ((n >> 6) & 1) * 0) * 64;
    // note: block spans a single qtile half (32 rows within one 64-row qtile)
    O0 = Opart + (size_t)(qtile * 2) * 4096 + r64 * 64;
    const float* O1 = O0 + 4096;
#pragma unroll
    for (int j8 = 0; j8 < 2; ++j8) {
      f32x4 a = *(const f32x4*)&O0[c0 + j8 * 4];
      f32x4 b = *(const f32x4*)&O1[c0 + j8 * 4];
      f32x4 vsum = (a + b) * inv;
#pragma unroll
      for (int e = 0; e < 4; ++e) ldso[row * 72 + pcmap(c0 + j8 * 4 + e)] = f2bf(vsum[e]);
    }
  }
  __syncthreads();

  const int lane = tid & 63, w = tid >> 6;
  const int r = lane & 15, q = lane >> 4;
  const int ntile = w & 1, mhalf = w >> 1;
  const int rowidx = ntile * 16 + r;
  short8 hf[2];
#pragma unroll
  for (int s = 0; s < 2; ++s)
    hf[s] = *(const short8*)&ldso[rowidx * 72 + s * 32 + q * 8];

  const int n = n0 + ntile * 16 + r;
#pragma unroll
  for (int mi = 0; mi < 2; ++mi) {
    int mt = mhalf * 2 + mi;
    f32x4 a = {};
#pragma unroll
    for (int s = 0; s < 2; ++s) {
      short8 wf = *(const short8*)(Wop + (mt * 16 + r) * 64 + s * 32 + q * 8);
      a = __builtin_amdgcn_mfma_f32_16x16x32_bf16(wf, hf[s], a, 0, 0, 0);
    }
    int m0 = mt * 16 + q * 4;
    f32x4 out = a + *(const f32x4*)&bo[m0] + *(const f32x4*)&res[(size_t)n * 64 + m0];
    *(f32x4*)&Y[(size_t)n * 64 + m0] = out;
  }
}

// ----------------------------- fused combine(bn1+bn2) + MLP (+relu +residual)
__global__ __launch_bounds__(256) void mlp_kernel(const float* __restrict__ t1,
                                                  const float* __restrict__ t0,
                                                  const float* __restrict__ s1,
                                                  const float* __restrict__ s2,
                                                  const float* __restrict__ g1,
                                                  const float* __restrict__ bb1,
                                                  const float* __restrict__ g2,
                                                  const float* __restrict__ bb2,
                                                  const float* __restrict__ W1,
                                                  const float* __restrict__ b1,
                                                  const float* __restrict__ W2,
                                                  const float* __restrict__ b2,
                                                  float* __restrict__ t4) {
  __shared__ float rows[32][68];
  __shared__ float mid[32][132];
  int t = threadIdx.x;
  int r0 = blockIdx.x * 32;
  for (int i = t; i < 2048; i += 256) {
    int rr = i >> 6, c = i & 63;
    int idx = (r0 + rr) * 64 + c;
    float m1 = s1[c] * (1.f / NN);
    float v1 = s1[64 + c] * (1.f / NN) - m1 * m1;
    float m2 = s2[c] * (1.f / NN);
    float v2 = s2[64 + c] * (1.f / NN) - m2 * m2;
    rows[rr][c] = (t1[idx] - m1) * rsqrtf(v1 + EPSV) * g1[c] + bb1[c] +
                  (t0[idx] - m2) * rsqrtf(v2 + EPSV) * g2[c] + bb2[c];
  }
  __syncthreads();
  int r = t >> 3;
  {
    int m0 = (t & 7) * 16;
    float acc[16];
#pragma unroll
    for (int j = 0; j < 16; ++j) acc[j] = b1[m0 + j];
    for (int k = 0; k < 64; ++k) {
      float xv = rows[r][k];
#pragma unroll
      for (int j = 0; j < 16; ++j) acc[j] = fmaf(xv, W1[k * 128 + m0 + j], acc[j]);
    }
#pragma unroll
    for (int j = 0; j < 16; ++j) mid[r][m0 + j] = fmaxf(acc[j], 0.f);
  }
  __syncthreads();
  {
    int c0 = (t & 7) * 8;
    float oc[8];
#pragma unroll
    for (int j = 0; j < 8; ++j) oc[j] = b2[c0 + j] + rows[r][c0 + j];
    for (int k = 0; k < 128; ++k) {
      float mv = mid[r][k];
#pragma unroll
      for (int j = 0; j < 8; ++j) oc[j] = fmaf(mv, W2[k * 64 + c0 + j], oc[j]);
    }
#pragma unroll
    for (int j = 0; j < 8; ++j) t4[(r0 + r) * 64 + c0 + j] = oc[j];
  }
}

// ------------------------------------------- BN3 + LayerNorm + ReLU (fused)
__global__ __launch_bounds__(256) void bn3_ln_relu(const float* __restrict__ t4,
                                                   const float* __restrict__ s3,
                                                   const float* __restrict__ g3,
                                                   const float* __restrict__ b3,
                                                   const float* __restrict__ lg,
                                                   const float* __restrict__ lb,
                                                   float* __restrict__ H,
                                                   u16* __restrict__ hb) {
  int wv = threadIdx.x >> 6, lane = threadIdx.x & 63;
  int n = blockIdx.x * 4 + wv;
  float m3 = s3[lane] * (1.f / NN);
  float v3 = s3[64 + lane] * (1.f / NN) - m3 * m3;
  float x = (t4[n * 64 + lane] - m3) * rsqrtf(v3 + EPSV) * g3[lane] + b3[lane];
  float s = x, ss = x * x;
  for (int o = 32; o > 0; o >>= 1) {
    s += __shfl_xor(s, o, 64);
    ss += __shfl_xor(ss, o, 64);
  }
  float m = s * (1.f / 64), v = ss * (1.f / 64) - m * m;
  float y = (x - m) * rsqrtf(v + EPSV) * lg[lane] + lb[lane];
  y = fmaxf(y, 0.f);
  H[n * 64 + lane] = y;
  hb[n * 64 + pcmap(lane)] = f2bf(y);
}

// ------------------------------------------- final GEMM (64x21) + log_softmax
__global__ __launch_bounds__(256) void final_kernel(const float* __restrict__ H,
                                                    const float* __restrict__ Wout,
                                                    const float* __restrict__ bout,
                                                    float* __restrict__ out) {
  int w = threadIdx.x >> 6, lane = threadIdx.x & 63;
  int n = blockIdx.x * 4 + w;
  const float* hr = H + n * 64;
  float acc = (lane < COUT) ? bout[lane] : -INFINITY;
  if (lane < COUT) {
#pragma unroll 16
    for (int k = 0; k < 64; ++k) acc = fmaf(hr[k], Wout[k * COUT + lane], acc);
  }
  float mx = acc;
  for (int o = 32; o > 0; o >>= 1) mx = fmaxf(mx, __shfl_xor(mx, o, 64));
  float e = __expf(acc - mx);
  float se = e;
  for (int o = 32; o > 0; o >>= 1) se += __shfl_xor(se, o, 64);
  float lse = mx + logf(se);
  if (lane < COUT) out[n * COUT + lane] = acc - lse;
}

// ================================================================ launch
extern "C" void kernel_launch(void* const* d_in, const int* in_sizes, int n_in,
                              void* d_out, int out_size, void* d_ws, size_t ws_size,
                              hipStream_t stream) {
  const float* x    = (const float*)d_in[0];
  const int*   ei   = (const int*)d_in[1];
  const float* W_in = (const float*)d_in[2];
  const float* b_in = (const float*)d_in[3];
  const float* gcnW = (const float*)d_in[4];
  const float* gcnB = (const float*)d_in[5];
  const float* Wqkv = (const float*)d_in[6];
  const float* bqkv = (const float*)d_in[7];
  const float* Wo   = (const float*)d_in[8];
  const float* bo   = (const float*)d_in[9];
  const float* bn1g = (const float*)d_in[10];
  const float* bn1b = (const float*)d_in[11];
  const float* bn2g = (const float*)d_in[12];
  const float* bn2b = (const float*)d_in[13];
  const float* bn3g = (const float*)d_in[14];
  const float* bn3b = (const float*)d_in[15];
  const float* W1   = (const float*)d_in[16];
  const float* b1   = (const float*)d_in[17];
  const float* W2   = (const float*)d_in[18];
  const float* b2   = (const float*)d_in[19];
  const float* lng  = (const float*)d_in[20];
  const float* lnb  = (const float*)d_in[21];
  const float* Wout = (const float*)d_in[22];
  const float* bout = (const float*)d_in[23];

  const int* src = ei;
  const int* dst = ei + NE;

  float* ws = (float*)d_ws;
  float* h     = ws + 0 * (NN * C);
  float* t0    = ws + 1 * (NN * C);   // xw, then oproj output
  float* t1    = ws + 2 * (NN * C);
  float* Opart = ws + 3 * (NN * C);   // 4MB: 128qt x 2ks x 64 x 64
  float* t4    = ws + 5 * (NN * C);   // mlp output
  u16* Qb  = (u16*)(ws + 6 * (NN * C));
  u16* Kb  = Qb + NN * C;
  u16* Vtb = Kb + NN * C;
  u16* hbb = Vtb + NN * C;
  u16* Wqp = hbb + NN * C;            // L x 192 x 64
  u16* Wop = Wqp + NL * 192 * 64;     // L x 64 x 64
  float* dinv = (float*)(Wop + NL * 64 * 64);
  float* statsAll = dinv + NN;        // 12 x 128
  float* Lpart = statsAll + 1536;     // 128 x 2 x 64
  int* degi   = (int*)(Lpart + 16384);
  int* rowptr = degi + NN;            // NN+1
  int* cursor = rowptr + NN + 8;
  int* esrc   = cursor + NN;          // NE

  dim3 B(256);

  // ---- setup: CSR + dinv + weight prep (deterministic; recomputed every call)
  zero_setup<<<32, B, 0, stream>>>(statsAll, degi);
  deg_kernel<<<NE / 256, B, 0, stream>>>(dst, degi);
  prefix_kernel<<<1, B, 0, stream>>>(degi, rowptr, cursor);
  dinv_kernel<<<NN / 256, B, 0, stream>>>(degi, dinv);
  fill_kernel<<<NE / 256, B, 0, stream>>>(src, dst, cursor, esrc);
  prep_weights<<<256, B, 0, stream>>>(Wqkv, Wo, Wqp, Wop);

  gemm_in_kernel<<<NN * C / 256, B, 0, stream>>>(x, W_in, b_in, h, hbb);

  for (int l = 0; l < NL; ++l) {
    float* s1 = statsAll + l * 384;
    float* s2 = s1 + 128;
    float* s3 = s1 + 256;

    // ---- local GCN branch + residual -> t1, stats1
    gcn_gemm_init<<<NN * C / 256, B, 0, stream>>>(h, gcnW + l * C * C, gcnB + l * C, dinv, t0, t1);
    gcn_gather<<<NN / 4, B, 0, stream>>>(rowptr, esrc, t0, dinv, t1);
    bn_stats<<<256, B, 0, stream>>>(t1, s1);

    // ---- global attention branch + residual -> t0, stats2
    qkv_mfma<<<NN / 32, 128, 0, stream>>>(hbb, Wqp + l * 192 * 64, bqkv + l * 192, Qb, Kb, Vtb);
    attn_mfma<<<256, 512, 0, stream>>>(Qb, Kb, Vtb, Opart, Lpart);
    oproj_mfma<<<NN / 32, B, 0, stream>>>(Opart, Lpart, Wop + l * 64 * 64, bo + l * C, h, t0);
    bn_stats<<<256, B, 0, stream>>>(t0, s2);

    // ---- combine + MLP -> t4, BN3 + LN + ReLU -> h (+hb)
    mlp_kernel<<<NN / 32, B, 0, stream>>>(t1, t0, s1, s2, bn1g + l * C, bn1b + l * C,
                                          bn2g + l * C, bn2b + l * C,
                                          W1 + l * C * 2 * C, b1 + l * 2 * C,
                                          W2 + l * 2 * C * C, b2 + l * C, t4);
    bn_stats<<<256, B, 0, stream>>>(t4, s3);
    bn3_ln_relu<<<NN / 4, B, 0, stream>>>(t4, s3, bn3g + l * C, bn3b + l * C,
                                          lng + l * C, lnb + l * C, h, hbb);
  }

  final_kernel<<<NN / 4, B, 0, stream>>>(h, Wout, bout, (float*)d_out);
}